// Round 11
// baseline (621.617 us; speedup 1.0000x reference)
//
#include <hip/hip_runtime.h>
#include <stdint.h>

#define N_ROWS 131072
#define DIMS 64
#define KCL 16
#define BETA 4.0f
#define NBLK 512            // N_ROWS / 256
#define CHUNK 16384         // elements per LDS sort chunk (16384 * 4B = 64KB LDS)
#define STH 1024            // sort threads per block (16 waves)
#define SEG_STRIDE 263168   // u32 elements per (dim,side)
#define VOFF (1u<<21)

typedef unsigned long long u64;
typedef unsigned int u32;

__device__ __forceinline__ u32 enc_f(float f) {
  u32 u = __float_as_uint(f);
  return (u & 0x80000000u) ? ~u : (u | 0x80000000u);
}
__device__ __forceinline__ float dec_f(u32 e) {
  u32 u = (e & 0x80000000u) ? (e & 0x7FFFFFFFu) : ~e;
  return __uint_as_float(u);
}
// unit (uint4) granularity bank swizzle
__device__ __forceinline__ u32 U4(u32 u) { return u ^ ((u >> 3) & 7u); }

#define CS(a,b,dd) { u32 _mn = min(a,b), _mx = max(a,b); a = (dd)?_mn:_mx; b = (dd)?_mx:_mn; }
#define CSV(A,B,D) { CS(A.x,B.x,D) CS(A.y,B.y,D) CS(A.z,B.z,D) CS(A.w,B.w,D) }

// bitonic merge of 16 named regs, direction D (strides 8,4,2,1)
#define M16G(a,b,c,d,e,f,g,h,i2,j2,k2,l,m,n,o,p,D) \
  CS(a,i2,D) CS(b,j2,D) CS(c,k2,D) CS(d,l,D) CS(e,m,D) CS(f,n,D) CS(g,o,D) CS(h,p,D) \
  CS(a,e,D)  CS(b,f,D)  CS(c,g,D)  CS(d,h,D) CS(i2,m,D) CS(j2,n,D) CS(k2,o,D) CS(l,p,D) \
  CS(a,c,D)  CS(b,d,D)  CS(e,g,D)  CS(f,h,D) CS(i2,k2,D) CS(j2,l,D) CS(m,o,D) CS(n,p,D) \
  CS(a,b,D)  CS(c,d,D)  CS(e,f,D)  CS(g,h,D) CS(i2,j2,D) CS(k2,l,D) CS(m,n,D) CS(o,p,D)

// full bitonic sort of 16 named regs with final direction D
#define SORT16G(a,b,c,d,e,f,g,h,i2,j2,k2,l,m,n,o,p,D) \
  CS(a,b,D) CS(c,d,!(D)) CS(e,f,D) CS(g,h,!(D)) CS(i2,j2,D) CS(k2,l,!(D)) CS(m,n,D) CS(o,p,!(D)) \
  CS(a,c,D) CS(b,d,D) CS(e,g,!(D)) CS(f,h,!(D)) CS(i2,k2,D) CS(j2,l,D) CS(m,o,!(D)) CS(n,p,!(D)) \
  CS(a,b,D) CS(c,d,D) CS(e,f,!(D)) CS(g,h,!(D)) CS(i2,j2,D) CS(k2,l,D) CS(m,n,!(D)) CS(o,p,!(D)) \
  CS(a,e,D) CS(b,f,D) CS(c,g,D) CS(d,h,D) CS(i2,m,!(D)) CS(j2,n,!(D)) CS(k2,o,!(D)) CS(l,p,!(D)) \
  CS(a,c,D) CS(b,d,D) CS(e,g,D) CS(f,h,D) CS(i2,k2,!(D)) CS(j2,l,!(D)) CS(m,o,!(D)) CS(n,p,!(D)) \
  CS(a,b,D) CS(c,d,D) CS(e,f,D) CS(g,h,D) CS(i2,j2,!(D)) CS(k2,l,!(D)) CS(m,n,!(D)) CS(o,p,!(D)) \
  M16G(a,b,c,d,e,f,g,h,i2,j2,k2,l,m,n,o,p,D)

#define MERGE16F(D) M16G(r0,r1,r2,r3,r4,r5,r6,r7,r8,r9,r10,r11,r12,r13,r14,r15,D)
#define SORT16F(D)  SORT16G(r0,r1,r2,r3,r4,r5,r6,r7,r8,r9,r10,r11,r12,r13,r14,r15,D)

#define LOADTILE16(src) \
  { uint4 _a0=src[U4(ub+0)],_a1=src[U4(ub+1)],_a2=src[U4(ub+2)],_a3=src[U4(ub+3)]; \
    r0=_a0.x;r1=_a0.y;r2=_a0.z;r3=_a0.w; r4=_a1.x;r5=_a1.y;r6=_a1.z;r7=_a1.w; \
    r8=_a2.x;r9=_a2.y;r10=_a2.z;r11=_a2.w; r12=_a3.x;r13=_a3.y;r14=_a3.z;r15=_a3.w; }

#define STORETILE16(dst) \
  { dst[U4(ub+0)]=make_uint4(r0,r1,r2,r3);   dst[U4(ub+1)]=make_uint4(r4,r5,r6,r7); \
    dst[U4(ub+2)]=make_uint4(r8,r9,r10,r11); dst[U4(ub+3)]=make_uint4(r12,r13,r14,r15); }

// ---- WAVE-LOCAL bitonic rounds: strides jtop..16 within this wave's 1024-run.
// DS ops of one wave execute in program order on CDNA -> no barriers needed.
// 2-fused trips {j, j/2} with ALL 64 lanes active (16-elem instances).
__device__ __forceinline__ void wave_tail(uint4* lds4, u32 RU, u32 Lw, u32 gbase,
                                          u32 k, u32 jtop, u32 lane)
{
  u32 j = jtop;
  while (j >= 32u) {
    u32 ud = j >> 3;                      // units between the 4 loads (= j/2 elems)
    if (lane < (Lw >> 4)) {               // 16-elem instances
      u32 bu = RU + (((lane & ~(ud - 1u)) << 2) | (lane & (ud - 1u)));
      bool up = (((gbase + (bu << 2)) & k) == 0u);
      uint4 A0 = lds4[U4(bu)],           A1 = lds4[U4(bu + ud)],
            A2 = lds4[U4(bu + 2u * ud)], A3 = lds4[U4(bu + 3u * ud)];
      CSV(A0,A2,up) CSV(A1,A3,up)         // stride j
      CSV(A0,A1,up) CSV(A2,A3,up)         // stride j/2
      lds4[U4(bu)] = A0;           lds4[U4(bu + ud)] = A1;
      lds4[U4(bu + 2u * ud)] = A2; lds4[U4(bu + 3u * ud)] = A3;
    }
    j >>= 2;
  }
  if (j == 16u) {                         // single stride-16 round
    u32 total = Lw >> 3;                  // 8-elem instances
    for (u32 inst = lane; inst < total; inst += 64u) {
      u32 bu = RU + (((inst & ~3u) << 1) | (inst & 3u));
      bool up = (((gbase + (bu << 2)) & k) == 0u);
      uint4 A = lds4[U4(bu)], B = lds4[U4(bu + 4u)];
      CSV(A,B,up)
      lds4[U4(bu)] = A; lds4[U4(bu + 4u)] = B;
    }
  }
}

// ---- BLOCK-WIDE fused cross-wave trips.
__device__ __forceinline__ void cross1(uint4* lds4, u32 Wn, u32 gb, u32 k, u32 jtop, u32 tid)
{
  u32 ud = jtop >> 2;
  u32 total = Wn >> 3;
  for (u32 inst = tid; inst < total; inst += STH) {
    u32 bu = ((inst & ~(ud - 1u)) << 1) | (inst & (ud - 1u));
    bool up = (((gb + (bu << 2)) & k) == 0u);
    uint4 A = lds4[U4(bu)], B = lds4[U4(bu + ud)];
    CSV(A,B,up)
    lds4[U4(bu)] = A; lds4[U4(bu + ud)] = B;
  }
}
__device__ __forceinline__ void cross2(uint4* lds4, u32 Wn, u32 gb, u32 k, u32 jtop, u32 tid)
{
  u32 ud = jtop >> 3;
  u32 total = Wn >> 4;
  for (u32 inst = tid; inst < total; inst += STH) {
    u32 bu = ((inst & ~(ud - 1u)) << 2) | (inst & (ud - 1u));
    bool up = (((gb + (bu << 2)) & k) == 0u);
    uint4 A0 = lds4[U4(bu)],            A1 = lds4[U4(bu + ud)],
          A2 = lds4[U4(bu + 2u * ud)],  A3 = lds4[U4(bu + 3u * ud)];
    CSV(A0,A2,up) CSV(A1,A3,up)
    CSV(A0,A1,up) CSV(A2,A3,up)
    lds4[U4(bu)] = A0;           lds4[U4(bu + ud)] = A1;
    lds4[U4(bu + 2u * ud)] = A2; lds4[U4(bu + 3u * ud)] = A3;
  }
}
__device__ __forceinline__ void cross3(uint4* lds4, u32 Wn, u32 gb, u32 k, u32 jtop, u32 tid)
{
  u32 ud = jtop >> 4;
  u32 total = Wn >> 5;
  for (u32 inst = tid; inst < total; inst += STH) {
    u32 bu = ((inst & ~(ud - 1u)) << 3) | (inst & (ud - 1u));
    bool up = (((gb + (bu << 2)) & k) == 0u);
    uint4 A0 = lds4[U4(bu)],            A1 = lds4[U4(bu + ud)],
          A2 = lds4[U4(bu + 2u * ud)],  A3 = lds4[U4(bu + 3u * ud)],
          A4 = lds4[U4(bu + 4u * ud)],  A5 = lds4[U4(bu + 5u * ud)],
          A6 = lds4[U4(bu + 6u * ud)],  A7 = lds4[U4(bu + 7u * ud)];
    CSV(A0,A4,up) CSV(A1,A5,up) CSV(A2,A6,up) CSV(A3,A7,up)
    CSV(A0,A2,up) CSV(A1,A3,up) CSV(A4,A6,up) CSV(A5,A7,up)
    CSV(A0,A1,up) CSV(A2,A3,up) CSV(A4,A5,up) CSV(A6,A7,up)
    lds4[U4(bu)] = A0;           lds4[U4(bu + ud)] = A1;
    lds4[U4(bu + 2u * ud)] = A2; lds4[U4(bu + 3u * ud)] = A3;
    lds4[U4(bu + 4u * ud)] = A4; lds4[U4(bu + 5u * ud)] = A5;
    lds4[U4(bu + 6u * ud)] = A6; lds4[U4(bu + 7u * ud)] = A7;
  }
}

// ---------------- K1: cluster assign + softmax filling + per-block histograms
__global__ __launch_bounds__(256) void k_assign(
    const float* __restrict__ x, const float* __restrict__ centers,
    const int* __restrict__ predT, int* __restrict__ predX,
    float* __restrict__ fill_sum, u32* __restrict__ histX, u32* __restrict__ histT)
{
  __shared__ float c[KCL][DIMS];
  __shared__ float cn[KCL];
  __shared__ float fs[KCL];
  __shared__ u32 hx[KCL], ht[KCL];
  int tid = threadIdx.x;
  for (int t = tid; t < KCL * DIMS; t += 256) c[t / DIMS][t % DIMS] = centers[t];
  if (tid < KCL) { fs[tid] = 0.f; hx[tid] = 0; ht[tid] = 0; }
  __syncthreads();
  if (tid < KCL) {
    float s = 0.f;
    for (int d = 0; d < DIMS; ++d) s += c[tid][d] * c[tid][d];
    cn[tid] = s;
  }
  __syncthreads();
  int i = blockIdx.x * 256 + tid;
  const float4* xr = (const float4*)(x + (size_t)i * DIMS);
  float dot[KCL];
#pragma unroll
  for (int k = 0; k < KCL; ++k) dot[k] = 0.f;
  for (int t = 0; t < DIMS / 4; ++t) {
    float4 v = xr[t];
#pragma unroll
    for (int k = 0; k < KCL; ++k)
      dot[k] += v.x * c[k][4 * t] + v.y * c[k][4 * t + 1] + v.z * c[k][4 * t + 2] + v.w * c[k][4 * t + 3];
  }
  float sc[KCL];
  float smin = 3.0e38f; int kmin = 0;
#pragma unroll
  for (int k = 0; k < KCL; ++k) {
    sc[k] = cn[k] - 2.f * dot[k];
    if (sc[k] < smin) { smin = sc[k]; kmin = k; }
  }
  float e[KCL]; float esum = 0.f;
#pragma unroll
  for (int k = 0; k < KCL; ++k) { e[k] = expf(-BETA * (sc[k] - smin)); esum += e[k]; }
  float inv = 1.f / esum;
#pragma unroll
  for (int k = 0; k < KCL; ++k) atomicAdd(&fs[k], e[k] * inv);
  predX[i] = kmin;
  atomicAdd(&hx[kmin], 1u);
  atomicAdd(&ht[predT[i]], 1u);
  __syncthreads();
  if (tid < KCL) {
    histX[blockIdx.x * KCL + tid] = hx[tid];
    histT[blockIdx.x * KCL + tid] = ht[tid];
    atomicAdd(&fill_sum[tid], fs[tid]);
  }
}

// ---------------- K2: scan hists -> bases, totals, m, w, p, pOff, mOff, nlo, loss_fil
__global__ __launch_bounds__(512) void k_scan(
    const u32* __restrict__ histX, const u32* __restrict__ histT,
    u32* __restrict__ baseX, u32* __restrict__ baseT,
    const float* __restrict__ fill_sum, const float* __restrict__ ftarget,
    int* __restrict__ m_out, float* __restrict__ w_out,
    int* __restrict__ p_out, int* __restrict__ pOff_out, int* __restrict__ mOff_out,
    int* __restrict__ nlo_out, float* __restrict__ loss_fil)
{
  __shared__ u32 part[2][KCL][17];
  __shared__ u32 tot[2][KCL];
  __shared__ float sq[KCL];
  __shared__ int sp[KCL];
  __shared__ int smv[KCL];
  int tid = threadIdx.x;
  int side = tid >> 8;
  int rem = tid & 255;
  int c = rem >> 4;
  int sub = rem & 15;
  const u32* hist = side ? histT : histX;
  u32* base = side ? baseT : baseX;
  int b0 = sub * 32;
  u32 s = 0;
  for (int b = b0; b < b0 + 32; ++b) s += hist[b * KCL + c];
  part[side][c][sub] = s;
  __syncthreads();
  if (sub == 0) {
    u32 run = 0;
    for (int t = 0; t < 16; ++t) { u32 v = part[side][c][t]; part[side][c][t] = run; run += v; }
    tot[side][c] = run;
  }
  __syncthreads();
  u32 run = part[side][c][sub];
  for (int b = b0; b < b0 + 32; ++b) { base[b * KCL + c] = run; run += hist[b * KCL + c]; }
  if (tid < KCL) {
    int m = min((int)tot[0][tid], (int)tot[1][tid]);
    m_out[tid] = m;
    smv[tid] = m;
    w_out[tid] = (m > 0) ? 1.f / ((float)m * (float)DIMS) : 0.f;
    int pp = 32;
    while (pp < m) pp <<= 1;
    sp[tid] = pp;
    p_out[tid] = pp;
    // nlo = pads residing in descending (odd) 16K chunks -> land at segment FRONT
    // after the full ascending merge; valid window is [nlo, nlo+m).
    int nlo = 0;
    if (pp > CHUNK) {
      int nch = pp / CHUNK;
      for (int j = 1; j < nch; j += 2) {
        int v = m - j * CHUNK;
        if (v < 0) v = 0;
        if (v > CHUNK) v = CHUNK;
        nlo += CHUNK - v;
      }
    }
    nlo_out[tid] = nlo;
    float d = fill_sum[tid] / (float)N_ROWS - ftarget[tid];
    sq[tid] = d * d;
  }
  __syncthreads();
  if (tid == 0) {
    float s2 = 0.f;
    int acc = 0, macc = 0;
    for (int k = 0; k < KCL; ++k) {
      s2 += sq[k];
      pOff_out[k] = acc;
      acc += sp[k];
      mOff_out[k] = macc;
      macc += smv[k];
    }
    pOff_out[KCL] = acc;
    mOff_out[KCL] = macc;
    *loss_fil = s2 / (float)KCL;
  }
}

// ---------------- K3: ordered within-cluster rank -> compact inverse index
__global__ __launch_bounds__(256) void k_rank(
    const int* __restrict__ predX, const int* __restrict__ predT,
    const u32* __restrict__ baseX, const u32* __restrict__ baseT,
    const int* __restrict__ mG, const int* __restrict__ mOffG,
    int* __restrict__ idxX, int* __restrict__ idxT)
{
  __shared__ int wcX[4][KCL], wcT[4][KCL];
  __shared__ int smo[KCL], sm2[KCL];
  int tid = threadIdx.x;
  int lane = tid & 63, wave = tid >> 6;
  if (tid < KCL) { smo[tid] = mOffG[tid]; sm2[tid] = mG[tid]; }
  int i = blockIdx.x * 256 + tid;
  int kx = predX[i], kt = predT[i];
  u64 below = (1ull << lane) - 1ull;
  int lrX = 0, lrT = 0;
  for (int cc = 0; cc < KCL; ++cc) {
    u64 mx = __ballot(kx == cc);
    u64 mt = __ballot(kt == cc);
    if (kx == cc) lrX = __popcll(mx & below);
    if (kt == cc) lrT = __popcll(mt & below);
    if (lane == 0) { wcX[wave][cc] = __popcll(mx); wcT[wave][cc] = __popcll(mt); }
  }
  __syncthreads();
  int wbX = 0, wbT = 0;
  for (int w2 = 0; w2 < wave; ++w2) { wbX += wcX[w2][kx]; wbT += wcT[w2][kt]; }
  int rX = (int)baseX[blockIdx.x * KCL + kx] + wbX + lrX;
  int rT = (int)baseT[blockIdx.x * KCL + kt] + wbT + lrT;
  if (rX < sm2[kx]) idxX[smo[kx] + rX] = i;
  if (rT < sm2[kt]) idxT[smo[kt] + rT] = i;
}

// ---------------- K4: gather rows into cluster-partitioned dim planes + pads.
// Coalesced row loads transposed through LDS (round-8 verified form).
__global__ __launch_bounds__(256) void k_gather(
    const float* __restrict__ x, const float* __restrict__ tgt,
    const int* __restrict__ idxX, const int* __restrict__ idxT,
    const int* __restrict__ pOffG, const int* __restrict__ mOffG,
    const int* __restrict__ mG, const int* __restrict__ pG,
    u32* __restrict__ valX, u32* __restrict__ valT, int d0, int Dbc)
{
  __shared__ int spOff[KCL + 1];
  __shared__ int smo[KCL], sm2[KCL], sp2[KCL];
  __shared__ float pl[32][257];       // planes[d_local][pos_local], padded
  __shared__ int sRowX[256], sRowT[256];
  __shared__ u32 sPv[256];
  int tid = threadIdx.x;
  if (tid <= KCL) spOff[tid] = pOffG[tid];
  if (tid < KCL) { smo[tid] = mOffG[tid]; sm2[tid] = mG[tid]; sp2[tid] = pG[tid]; }
  __syncthreads();
  int pos = blockIdx.x * 256 + tid;
  bool inr = pos < spOff[KCL];
  int c = 0, rel = 0;
  bool vld = false;
  if (inr) {
#pragma unroll
    for (int cc = 1; cc < KCL; ++cc) c += (pos >= spOff[cc]) ? 1 : 0;
    rel = pos - spOff[c];
    vld = rel < sm2[c];
  }

  if (Dbc == 64) {
    int w = vld ? (smo[c] + rel) : 0;
    sRowX[tid] = vld ? idxX[w] : -1;
    sRowT[tid] = vld ? idxT[w] : -1;
    sPv[tid] = inr ? ((sp2[c] > CHUNK && ((rel >> 14) & 1)) ? 0u : 0xFFFFFFFFu) : 0u;
    __syncthreads();
#pragma unroll
    for (int side = 0; side < 2; ++side) {
      const float* src = side ? tgt : x;
      const int* sRow = side ? sRowT : sRowX;
      u32* dst = side ? valT : valX;
#pragma unroll
      for (int h = 0; h < 2; ++h) {
        int h0 = h * 32;
        for (int idx = tid; idx < 256 * 8; idx += 256) {
          int r = idx >> 3, f = idx & 7;
          int row = sRow[r];
          if (row >= 0) {
            float4 v = *(const float4*)(src + (size_t)row * DIMS + d0 + h0 + f * 4);
            pl[f * 4 + 0][r] = v.x;
            pl[f * 4 + 1][r] = v.y;
            pl[f * 4 + 2][r] = v.z;
            pl[f * 4 + 3][r] = v.w;
          }
        }
        __syncthreads();
        if (inr) {
          bool v2 = sRow[tid] >= 0;
          u32 pv = sPv[tid];
          for (int dl = 0; dl < 32; ++dl) {
            u32 e = v2 ? enc_f(pl[dl][tid]) : pv;
            dst[(size_t)(h0 + dl) * SEG_STRIDE + pos] = e;
          }
        }
        __syncthreads();
      }
    }
    return;
  }

  // ---- generic fallback (Dbc != 64)
  if (!inr) return;
  u32* dx = valX + pos;
  u32* dt = valT + pos;
  if (vld) {
    int w = smo[c] + rel;
    int iX = idxX[w], iT = idxT[w];
    const float* xr = x + (size_t)iX * DIMS + d0;
    const float* tr = tgt + (size_t)iT * DIMS + d0;
    for (int d = 0; d < Dbc; ++d) {
      dx[(size_t)d * SEG_STRIDE] = enc_f(xr[d]);
      dt[(size_t)d * SEG_STRIDE] = enc_f(tr[d]);
    }
  } else {
    u32 pv = (sp2[c] > CHUNK && ((rel >> 14) & 1)) ? 0u : 0xFFFFFFFFu;
    for (int d = 0; d < Dbc; ++d) {
      dx[(size_t)d * SEG_STRIDE] = pv;
      dt[(size_t)d * SEG_STRIDE] = pv;
    }
  }
}

// ---------------- K5a: per-16K-chunk windowed bitonic sort of X planes
// (round-8 body verbatim; grid y in [0, Dbc) selects the X plane).
__global__ __launch_bounds__(STH, 8) void k_sortX(
    u32* __restrict__ vbase, const int* __restrict__ pG, const int* __restrict__ pOffG,
    const int* __restrict__ mG)
{
  __shared__ __align__(16) u32 lds[CHUNK];
  uint4* lds4 = (uint4*)lds;
  int t = blockIdx.x, c = -1, sub = 0, acc = 0;
  for (int cc = 0; cc < KCL; ++cc) {
    int pc0 = pG[cc];
    int nc = (pc0 > CHUNK) ? (pc0 / CHUNK) : 1;
    if (t < acc + nc) { c = cc; sub = t - acc; break; }
    acc += nc;
  }
  if (c < 0) return;
  int pc = pG[c];
  u32 CH = (u32)min(pc, CHUNK);
  u32 gb = (u32)sub * (u32)CHUNK;
  int v = mG[c] - (int)gb;                 // valid elements in this chunk
  if (v > (int)CH) v = (int)CH;
  if (v <= 0) return;                      // all-pad chunk
  u32 W = 32u;                             // sort window = next pow2 >= v
  while (W < (u32)v) W <<= 1;
  if (W > CH) W = CH;
  bool desc = (pc > CHUNK) && (sub & 1);
  u32 inv = desc ? 0xFFFFFFFFu : 0u;
  u32* seg = vbase + (size_t)blockIdx.y * SEG_STRIDE + pOffG[c] + gb;
  uint4* gp4 = (uint4*)seg;
  u32 tid = threadIdx.x;
  u32 lane = tid & 63u;
  u32 wv = tid >> 6;
  u32 ub = tid << 2;            // first unit of this thread's 16-elem tile
  u32 bas = tid << 4;           // first element index (window-local)
  bool act = (bas < W);
  u32 RU = wv << 8;             // wave run base, units
  u32 runBase = wv << 10;       // wave run base, elements
  bool wact = (runBase < W);
  u32 Lw = W - runBase; if (Lw > 1024u) Lw = 1024u;
  u32 r0,r1,r2,r3,r4,r5,r6,r7,r8,r9,r10,r11,r12,r13,r14,r15;

  // ---- Phase A: global -> regs, 16-sort, wave-local stages (no barriers)
  if (act) {
    uint4 a0 = gp4[ub + 0], a1 = gp4[ub + 1], a2 = gp4[ub + 2], a3 = gp4[ub + 3];
    r0 = a0.x^inv; r1 = a0.y^inv; r2  = a0.z^inv; r3  = a0.w^inv;
    r4 = a1.x^inv; r5 = a1.y^inv; r6  = a1.z^inv; r7  = a1.w^inv;
    r8 = a2.x^inv; r9 = a2.y^inv; r10 = a2.z^inv; r11 = a2.w^inv;
    r12 = a3.x^inv; r13 = a3.y^inv; r14 = a3.z^inv; r15 = a3.w^inv;
    bool D = ((bas & 16u) == 0u);
    SORT16F(D);
    STORETILE16(lds4);
  }
  if (wact) {
    for (u32 k = 32u; k <= Lw; k <<= 1) {
      wave_tail(lds4, RU, Lw, 0u, k, k >> 1, lane);
      if (act) {
        LOADTILE16(lds4);
        bool D = ((bas & k) == 0u);
        MERGE16F(D);
        STORETILE16(lds4);
      }
    }
  }

  // ---- Phase B: cross-wave stages (W >= 2048)
  if (W >= 2048u) {
    __syncthreads();
    for (u32 k = 2048u; k <= W; k <<= 1) {
      u32 jt = k >> 1;
      if (jt >= 8192u) {                  // k = 16384: strides 8192..1024
        cross3(lds4, W, 0u, k, 8192u, tid);
        __syncthreads();
        cross1(lds4, W, 0u, k, 1024u, tid);
        __syncthreads();
      } else if (jt == 4096u) {
        cross3(lds4, W, 0u, k, 4096u, tid);
        __syncthreads();
      } else if (jt == 2048u) {
        cross2(lds4, W, 0u, k, 2048u, tid);
        __syncthreads();
      } else {
        cross1(lds4, W, 0u, k, 1024u, tid);
        __syncthreads();
      }
      if (wact) {
        wave_tail(lds4, RU, Lw, 0u, k, 512u, lane);
        if (act) {
          LOADTILE16(lds4);
          bool D = ((bas & k) == 0u);
          MERGE16F(D);
          STORETILE16(lds4);
        }
      }
      if (k < W) __syncthreads();
    }
  }

  // ---- lane-striped dense write-out (full cache lines)
  __syncthreads();
  for (u32 uu = tid; (uu << 2) < W; uu += STH) {
    uint4 q = lds4[U4(uu)];
    q.x ^= inv; q.y ^= inv; q.z ^= inv; q.w ^= inv;
    gp4[uu] = q;
  }
}

// ---------------- K5b: sort T planes + fused small-cluster reduce.
// Same verified body on segT = X plane + Dbc*SEG_STRIDE. Big clusters: XOR
// write-out (feeds gpass/gfinish). Small clusters: NO write-out — pair the
// sorted T tile (LDS) against the sorted X tile (global, just written by
// k_sortX, L2-hot) and accumulate the weighted |diff| into lossAcc.
__global__ __launch_bounds__(STH, 8) void k_sortT(
    u32* __restrict__ vbase, const int* __restrict__ pG, const int* __restrict__ pOffG,
    const int* __restrict__ mG, const float* __restrict__ wG,
    float* __restrict__ lossAcc, int Dbc)
{
  __shared__ __align__(16) u32 lds[CHUNK];
  uint4* lds4 = (uint4*)lds;
  int t = blockIdx.x, c = -1, sub = 0, acc = 0;
  for (int cc = 0; cc < KCL; ++cc) {
    int pc0 = pG[cc];
    int nc = (pc0 > CHUNK) ? (pc0 / CHUNK) : 1;
    if (t < acc + nc) { c = cc; sub = t - acc; break; }
    acc += nc;
  }
  if (c < 0) return;
  int pc = pG[c];
  u32 CH = (u32)min(pc, CHUNK);
  u32 gb = (u32)sub * (u32)CHUNK;
  int v = mG[c] - (int)gb;                 // valid elements in this chunk
  if (v > (int)CH) v = (int)CH;
  if (v <= 0) return;                      // all-pad chunk
  u32 W = 32u;                             // sort window = next pow2 >= v
  while (W < (u32)v) W <<= 1;
  if (W > CH) W = CH;
  bool big = (pc > CHUNK);
  bool desc = big && (sub & 1);
  u32 inv = desc ? 0xFFFFFFFFu : 0u;
  u32* segX = vbase + (size_t)blockIdx.y * SEG_STRIDE + pOffG[c] + gb;
  u32* segT = segX + (size_t)Dbc * SEG_STRIDE;
  uint4* gp4 = (uint4*)segT;
  const uint4* gpX4 = (const uint4*)segX;
  u32 tid = threadIdx.x;
  u32 lane = tid & 63u;
  u32 wv = tid >> 6;
  u32 ub = tid << 2;            // first unit of this thread's 16-elem tile
  u32 bas = tid << 4;           // first element index (window-local)
  bool act = (bas < W);
  u32 RU = wv << 8;             // wave run base, units
  u32 runBase = wv << 10;       // wave run base, elements
  bool wact = (runBase < W);
  u32 Lw = W - runBase; if (Lw > 1024u) Lw = 1024u;
  u32 r0,r1,r2,r3,r4,r5,r6,r7,r8,r9,r10,r11,r12,r13,r14,r15;

  // ---- Phase A: global -> regs, 16-sort, wave-local stages (no barriers)
  if (act) {
    uint4 a0 = gp4[ub + 0], a1 = gp4[ub + 1], a2 = gp4[ub + 2], a3 = gp4[ub + 3];
    r0 = a0.x^inv; r1 = a0.y^inv; r2  = a0.z^inv; r3  = a0.w^inv;
    r4 = a1.x^inv; r5 = a1.y^inv; r6  = a1.z^inv; r7  = a1.w^inv;
    r8 = a2.x^inv; r9 = a2.y^inv; r10 = a2.z^inv; r11 = a2.w^inv;
    r12 = a3.x^inv; r13 = a3.y^inv; r14 = a3.z^inv; r15 = a3.w^inv;
    bool D = ((bas & 16u) == 0u);
    SORT16F(D);
    STORETILE16(lds4);
  }
  if (wact) {
    for (u32 k = 32u; k <= Lw; k <<= 1) {
      wave_tail(lds4, RU, Lw, 0u, k, k >> 1, lane);
      if (act) {
        LOADTILE16(lds4);
        bool D = ((bas & k) == 0u);
        MERGE16F(D);
        STORETILE16(lds4);
      }
    }
  }

  // ---- Phase B: cross-wave stages (W >= 2048)
  if (W >= 2048u) {
    __syncthreads();
    for (u32 k = 2048u; k <= W; k <<= 1) {
      u32 jt = k >> 1;
      if (jt >= 8192u) {                  // k = 16384: strides 8192..1024
        cross3(lds4, W, 0u, k, 8192u, tid);
        __syncthreads();
        cross1(lds4, W, 0u, k, 1024u, tid);
        __syncthreads();
      } else if (jt == 4096u) {
        cross3(lds4, W, 0u, k, 4096u, tid);
        __syncthreads();
      } else if (jt == 2048u) {
        cross2(lds4, W, 0u, k, 2048u, tid);
        __syncthreads();
      } else {
        cross1(lds4, W, 0u, k, 1024u, tid);
        __syncthreads();
      }
      if (wact) {
        wave_tail(lds4, RU, Lw, 0u, k, 512u, lane);
        if (act) {
          LOADTILE16(lds4);
          bool D = ((bas & k) == 0u);
          MERGE16F(D);
          STORETILE16(lds4);
        }
      }
      if (k < W) __syncthreads();
    }
  }
  __syncthreads();

  if (big) {
    // lane-striped dense write-out (full cache lines)
    for (u32 uu = tid; (uu << 2) < W; uu += STH) {
      uint4 q = lds4[U4(uu)];
      q.x ^= inv; q.y ^= inv; q.z ^= inv; q.w ^= inv;
      gp4[uu] = q;
    }
    return;
  }

  // ---- fused reduce (small cluster: whole cluster in this chunk, window [0,m))
  float s = 0.f;
  if (act) {
    LOADTILE16(lds4);                     // r0..r15 = sorted T tile
    uint4 b0 = gpX4[ub + 0], b1 = gpX4[ub + 1], b2 = gpX4[ub + 2], b3 = gpX4[ub + 3];
    u32 vv = (u32)v;
    if (bas + 0u  < vv) s += fabsf(dec_f(b0.x) - dec_f(r0));
    if (bas + 1u  < vv) s += fabsf(dec_f(b0.y) - dec_f(r1));
    if (bas + 2u  < vv) s += fabsf(dec_f(b0.z) - dec_f(r2));
    if (bas + 3u  < vv) s += fabsf(dec_f(b0.w) - dec_f(r3));
    if (bas + 4u  < vv) s += fabsf(dec_f(b1.x) - dec_f(r4));
    if (bas + 5u  < vv) s += fabsf(dec_f(b1.y) - dec_f(r5));
    if (bas + 6u  < vv) s += fabsf(dec_f(b1.z) - dec_f(r6));
    if (bas + 7u  < vv) s += fabsf(dec_f(b1.w) - dec_f(r7));
    if (bas + 8u  < vv) s += fabsf(dec_f(b2.x) - dec_f(r8));
    if (bas + 9u  < vv) s += fabsf(dec_f(b2.y) - dec_f(r9));
    if (bas + 10u < vv) s += fabsf(dec_f(b2.z) - dec_f(r10));
    if (bas + 11u < vv) s += fabsf(dec_f(b2.w) - dec_f(r11));
    if (bas + 12u < vv) s += fabsf(dec_f(b3.x) - dec_f(r12));
    if (bas + 13u < vv) s += fabsf(dec_f(b3.y) - dec_f(r13));
    if (bas + 14u < vv) s += fabsf(dec_f(b3.z) - dec_f(r14));
    if (bas + 15u < vv) s += fabsf(dec_f(b3.w) - dec_f(r15));
  }
  s *= wG[c];
  for (int o = 32; o > 0; o >>= 1) s += __shfl_down(s, o, 64);
  __syncthreads();                        // all LDS tile reads done before reuse
  float* lf = (float*)lds;
  if (lane == 0) lf[wv] = s;
  __syncthreads();
  if (tid == 0) {
    float tt = 0.f;
#pragma unroll
    for (int i2 = 0; i2 < STH / 64; ++i2) tt += lf[i2];
    atomicAdd(lossAcc, tt);
  }
}

// ---------------- K6: global bitonic pass for big segments (j >= CHUNK).
__global__ __launch_bounds__(256) void k_gpass(
    u32* __restrict__ vbase, const int* __restrict__ pG, const int* __restrict__ pOffG,
    int kk, int j)
{
  u32* base = vbase + (size_t)blockIdx.y * SEG_STRIDE;
  int pb[KCL]; int tot = 0;
#pragma unroll
  for (int c = 0; c < KCL; ++c) {
    pb[c] = tot;
    int pc = pG[c];
    if (pc >= kk) tot += pc >> 1;
  }
  for (int g4 = (blockIdx.x * 256 + threadIdx.x) << 2; g4 < tot; g4 += gridDim.x * 256 * 4) {
    int c = 0;
#pragma unroll
    for (int cc = 1; cc < KCL; ++cc) c += (g4 >= pb[cc]) ? 1 : 0;
    int u = g4 - pb[c];
    int i = ((u & ~(j - 1)) << 1) | (u & (j - 1));
    bool up = ((i & kk) == 0);
    u32* s2 = base + pOffG[c];
    uint4 A = *(const uint4*)(s2 + i);
    uint4 B = *(const uint4*)(s2 + i + j);
    CS(A.x, B.x, up) CS(A.y, B.y, up) CS(A.z, B.z, up) CS(A.w, B.w, up)
    *(uint4*)(s2 + i) = A;
    *(uint4*)(s2 + i + j) = B;
  }
}

// ---------------- K7: finish big-segment stage (strides <= 8192) in 64KB LDS.
__global__ __launch_bounds__(STH) void k_gfinish(
    u32* __restrict__ vbase, const int* __restrict__ pG, const int* __restrict__ pOffG, int kk)
{
  __shared__ __align__(16) u32 lds[CHUNK];
  uint4* lds4 = (uint4*)lds;
  int t = blockIdx.x, c = -1, sub = 0, acc = 0;
  for (int cc = 0; cc < KCL; ++cc) {
    int pc = pG[cc];
    if (pc < kk) continue;
    int nc = pc / CHUNK;
    if (t < acc + nc) { c = cc; sub = t - acc; break; }
    acc += nc;
  }
  if (c < 0) return;
  u32 gb = (u32)sub * (u32)CHUNK;
  u32* seg = vbase + (size_t)blockIdx.y * SEG_STRIDE + pOffG[c] + gb;
  uint4* gp4 = (uint4*)seg;
  u32 tid = threadIdx.x;
  u32 lane = tid & 63u;
  u32 wv = tid >> 6;
  u32 RU = wv << 8;
  u32 ub = tid << 2;
  u32 bas = tid << 4;
  u32 r0,r1,r2,r3,r4,r5,r6,r7,r8,r9,r10,r11,r12,r13,r14,r15;

  for (u32 uu = tid; uu < CHUNK / 4; uu += STH) lds4[U4(uu)] = gp4[uu];
  __syncthreads();
  cross3(lds4, (u32)CHUNK, gb, (u32)kk, 8192u, tid);   // strides 8192..2048
  __syncthreads();
  cross1(lds4, (u32)CHUNK, gb, (u32)kk, 1024u, tid);   // stride 1024
  __syncthreads();
  wave_tail(lds4, RU, 1024u, gb, (u32)kk, 512u, lane); // strides 512..16
  {
    LOADTILE16(lds4);
    bool up = (((gb + bas) & (u32)kk) == 0u);
    MERGE16F(up);
    STORETILE16(lds4);
  }
  __syncthreads();
  for (u32 uu = tid; uu < CHUNK / 4; uu += STH) gp4[uu] = lds4[U4(uu)];
}

// ---------------- K8: |diff| reduce over BIG clusters only (p > CHUNK).
__global__ __launch_bounds__(256) void k_reduce_big(
    const u32* __restrict__ valX, const u32* __restrict__ valT,
    const int* __restrict__ pOffG, const int* __restrict__ mG,
    const int* __restrict__ pG, const int* __restrict__ nloG,
    const float* __restrict__ wG, float* __restrict__ lossAcc)
{
  __shared__ int bnd[KCL + 1];
  __shared__ int spOff[KCL];
  __shared__ int snlo[KCL];
  __shared__ float swt[KCL];
  __shared__ float red[256];
  int tid = threadIdx.x;
  if (tid == 0) {
    int mb = 0;
    for (int k = 0; k < KCL; ++k) { bnd[k] = mb; if (pG[k] > CHUNK) mb += mG[k]; }
    bnd[KCL] = mb;
  }
  if (tid < KCL) { spOff[tid] = pOffG[tid]; snlo[tid] = nloG[tid]; swt[tid] = wG[tid]; }
  __syncthreads();
  int M = bnd[KCL];
  int d = blockIdx.y;
  const u32* vx = valX + (size_t)d * SEG_STRIDE;
  const u32* vt = valT + (size_t)d * SEG_STRIDE;
  float s = 0.f;
  for (int w = blockIdx.x * 256 + tid; w < M; w += gridDim.x * 256) {
    int c = 0;
#pragma unroll
    for (int cc = 1; cc < KCL; ++cc) c += (w >= bnd[cc]) ? 1 : 0;
    int pos = spOff[c] + snlo[c] + (w - bnd[c]);
    float a = dec_f(vx[pos]), b = dec_f(vt[pos]);
    s += fabsf(a - b) * swt[c];
  }
  red[tid] = s;
  __syncthreads();
  for (int st = 128; st > 0; st >>= 1) {
    if (tid < st) red[tid] += red[tid + st];
    __syncthreads();
  }
  if (tid == 0 && red[0] != 0.f) atomicAdd(lossAcc, red[0]);
}

// ---------------- K9: final scalar
__global__ void k_final(const float* __restrict__ lossAcc, const float* __restrict__ loss_fil,
                        float* __restrict__ out)
{
  out[0] = *lossAcc + *loss_fil;
}

extern "C" void kernel_launch(void* const* d_in, const int* in_sizes, int n_in,
                              void* d_out, int out_size, void* d_ws, size_t ws_size,
                              hipStream_t stream)
{
  const float* x       = (const float*)d_in[0];
  const float* centers = (const float*)d_in[1];
  const float* ftarget = (const float*)d_in[2];
  const float* tgt     = (const float*)d_in[3];
  const int*   predT   = (const int*)d_in[4];
  float* out = (float*)d_out;

  char* ws = (char*)d_ws;
  float* fill_sum = (float*)(ws + 0);       // 16 f (zeroed)
  float* lossAcc  = (float*)(ws + 64);      // zeroed
  float* loss_fil = (float*)(ws + 68);      // zeroed
  int*   m_buf    = (int*)(ws + 128);
  float* w_buf    = (float*)(ws + 192);
  int*   p_buf    = (int*)(ws + 256);
  int*   pOff     = (int*)(ws + 320);       // 17 ints
  int*   mOff     = (int*)(ws + 400);       // 17 ints
  u32* histX = (u32*)(ws + 512);            // 512*16*4 = 32768
  u32* histT = (u32*)(ws + 512 + 32768);
  u32* baseX = (u32*)(ws + 512 + 65536);
  u32* baseT = (u32*)(ws + 512 + 98304);
  int* predX = (int*)(ws + 131584);         // 524288
  int* idxX  = (int*)(ws + 655872);         // 524288 (compact, Sum(m) <= 131072)
  int* idxT  = (int*)(ws + 1180160);        // 524288
  int* nlo_buf = (int*)(ws + 1704448);      // 16 ints
  u32* vbase = (u32*)(ws + VOFF);

  size_t avail_elems = (ws_size > VOFF) ? ((ws_size - VOFF) / 4) : 0;
  int Db = (int)(avail_elems / (2ull * SEG_STRIDE));
  if (Db > DIMS) Db = DIMS;
  if (Db >= 4) Db &= ~3;
  if (Db < 1) Db = 1;

  hipMemsetAsync(ws, 0, 128, stream);
  k_assign<<<NBLK, 256, 0, stream>>>(x, centers, predT, predX, fill_sum, histX, histT);
  k_scan<<<1, 512, 0, stream>>>(histX, histT, baseX, baseT, fill_sum, ftarget,
                                m_buf, w_buf, p_buf, pOff, mOff, nlo_buf, loss_fil);
  k_rank<<<NBLK, 256, 0, stream>>>(predX, predT, baseX, baseT, m_buf, mOff, idxX, idxT);

  for (int d0 = 0; d0 < DIMS; d0 += Db) {
    int Dbc = (Db < DIMS - d0) ? Db : (DIMS - d0);
    u32* valX = vbase;
    u32* valT = vbase + (size_t)Dbc * SEG_STRIDE;
    // 1028 * 256 = 263168 >= worst-case Sum(p); values + pads in one pass
    k_gather<<<1028, 256, 0, stream>>>(x, tgt, idxX, idxT, pOff, mOff, m_buf, p_buf,
                                       valX, valT, d0, Dbc);
    // sort X planes (writes sorted X back), then sort T planes with fused
    // small-cluster reduce against the L2-hot sorted X
    k_sortX<<<dim3(28, Dbc), STH, 0, stream>>>(vbase, p_buf, pOff, m_buf);
    k_sortT<<<dim3(28, Dbc), STH, 0, stream>>>(vbase, p_buf, pOff, m_buf,
                                               w_buf, lossAcc, Dbc);
    // parallel merge stages for clusters with p > 16384 (early-exit when none)
    for (int kk = 2 * CHUNK; kk <= N_ROWS; kk <<= 1) {
      int gx = (kk == 2 * CHUNK) ? 32 : 8;
      for (int j = kk >> 1; j >= CHUNK; j >>= 1)
        k_gpass<<<dim3(gx, 2 * Dbc), 256, 0, stream>>>(vbase, p_buf, pOff, kk, j);
      k_gfinish<<<dim3(18, 2 * Dbc), STH, 0, stream>>>(vbase, p_buf, pOff, kk);
    }
    // reduce over big clusters only (small clusters fused into k_sortT)
    k_reduce_big<<<dim3(8, Dbc), 256, 0, stream>>>(valX, valT, pOff, m_buf, p_buf,
                                                   nlo_buf, w_buf, lossAcc);
  }
  k_final<<<1, 1, 0, stream>>>(lossAcc, loss_fil, out);
}

// Round 12
// 611.650 us; speedup vs baseline: 1.0163x; 1.0163x over previous
//
#include <hip/hip_runtime.h>
#include <stdint.h>

#define N_ROWS 131072
#define DIMS 64
#define KCL 16
#define BETA 4.0f
#define NBLK 512            // N_ROWS / 256
#define CHUNK 16384         // elements per LDS sort chunk (16384 * 4B = 64KB LDS)
#define STH 1024            // sort threads per block (16 waves)
#define SEG_STRIDE 263168   // u32 elements per (dim,side)
#define VOFF (1u<<21)

typedef unsigned long long u64;
typedef unsigned int u32;

__device__ __forceinline__ u32 enc_f(float f) {
  u32 u = __float_as_uint(f);
  return (u & 0x80000000u) ? ~u : (u | 0x80000000u);
}
__device__ __forceinline__ float dec_f(u32 e) {
  u32 u = (e & 0x80000000u) ? (e & 0x7FFFFFFFu) : ~e;
  return __uint_as_float(u);
}
// unit (uint4) granularity bank swizzle
__device__ __forceinline__ u32 U4(u32 u) { return u ^ ((u >> 3) & 7u); }

#define CS(a,b,dd) { u32 _mn = min(a,b), _mx = max(a,b); a = (dd)?_mn:_mx; b = (dd)?_mx:_mn; }
#define CSV(A,B,D) { CS(A.x,B.x,D) CS(A.y,B.y,D) CS(A.z,B.z,D) CS(A.w,B.w,D) }

// bitonic merge of 16 named regs, direction D (strides 8,4,2,1)
#define M16G(a,b,c,d,e,f,g,h,i2,j2,k2,l,m,n,o,p,D) \
  CS(a,i2,D) CS(b,j2,D) CS(c,k2,D) CS(d,l,D) CS(e,m,D) CS(f,n,D) CS(g,o,D) CS(h,p,D) \
  CS(a,e,D)  CS(b,f,D)  CS(c,g,D)  CS(d,h,D) CS(i2,m,D) CS(j2,n,D) CS(k2,o,D) CS(l,p,D) \
  CS(a,c,D)  CS(b,d,D)  CS(e,g,D)  CS(f,h,D) CS(i2,k2,D) CS(j2,l,D) CS(m,o,D) CS(n,p,D) \
  CS(a,b,D)  CS(c,d,D)  CS(e,f,D)  CS(g,h,D) CS(i2,j2,D) CS(k2,l,D) CS(m,n,D) CS(o,p,D)

// full bitonic sort of 16 named regs with final direction D
#define SORT16G(a,b,c,d,e,f,g,h,i2,j2,k2,l,m,n,o,p,D) \
  CS(a,b,D) CS(c,d,!(D)) CS(e,f,D) CS(g,h,!(D)) CS(i2,j2,D) CS(k2,l,!(D)) CS(m,n,D) CS(o,p,!(D)) \
  CS(a,c,D) CS(b,d,D) CS(e,g,!(D)) CS(f,h,!(D)) CS(i2,k2,D) CS(j2,l,D) CS(m,o,!(D)) CS(n,p,!(D)) \
  CS(a,b,D) CS(c,d,D) CS(e,f,!(D)) CS(g,h,!(D)) CS(i2,j2,D) CS(k2,l,D) CS(m,n,!(D)) CS(o,p,!(D)) \
  CS(a,e,D) CS(b,f,D) CS(c,g,D) CS(d,h,D) CS(i2,m,!(D)) CS(j2,n,!(D)) CS(k2,o,!(D)) CS(l,p,!(D)) \
  CS(a,c,D) CS(b,d,D) CS(e,g,D) CS(f,h,D) CS(i2,k2,!(D)) CS(j2,l,!(D)) CS(m,o,!(D)) CS(n,p,!(D)) \
  CS(a,b,D) CS(c,d,D) CS(e,f,D) CS(g,h,D) CS(i2,j2,!(D)) CS(k2,l,!(D)) CS(m,n,!(D)) CS(o,p,!(D)) \
  M16G(a,b,c,d,e,f,g,h,i2,j2,k2,l,m,n,o,p,D)

#define MERGE16F(D) M16G(r0,r1,r2,r3,r4,r5,r6,r7,r8,r9,r10,r11,r12,r13,r14,r15,D)
#define SORT16F(D)  SORT16G(r0,r1,r2,r3,r4,r5,r6,r7,r8,r9,r10,r11,r12,r13,r14,r15,D)

#define LOADTILE16(src) \
  { uint4 _a0=src[U4(ub+0)],_a1=src[U4(ub+1)],_a2=src[U4(ub+2)],_a3=src[U4(ub+3)]; \
    r0=_a0.x;r1=_a0.y;r2=_a0.z;r3=_a0.w; r4=_a1.x;r5=_a1.y;r6=_a1.z;r7=_a1.w; \
    r8=_a2.x;r9=_a2.y;r10=_a2.z;r11=_a2.w; r12=_a3.x;r13=_a3.y;r14=_a3.z;r15=_a3.w; }

#define STORETILE16(dst) \
  { dst[U4(ub+0)]=make_uint4(r0,r1,r2,r3);   dst[U4(ub+1)]=make_uint4(r4,r5,r6,r7); \
    dst[U4(ub+2)]=make_uint4(r8,r9,r10,r11); dst[U4(ub+3)]=make_uint4(r12,r13,r14,r15); }

// ---- WAVE-LOCAL bitonic rounds: strides jtop..16 within this wave's 1024-run.
// DS ops of one wave execute in program order on CDNA -> no barriers needed.
// gbase shifts the element index used for direction (window-local directions).
__device__ __forceinline__ void wave_tail(uint4* lds4, u32 RU, u32 Lw, u32 gbase,
                                          u32 k, u32 jtop, u32 lane)
{
  u32 j = jtop;
  while (j >= 32u) {
    u32 ud = j >> 3;                      // units between the 4 loads (= j/2 elems)
    if (lane < (Lw >> 4)) {               // 16-elem instances
      u32 bu = RU + (((lane & ~(ud - 1u)) << 2) | (lane & (ud - 1u)));
      bool up = (((gbase + (bu << 2)) & k) == 0u);
      uint4 A0 = lds4[U4(bu)],           A1 = lds4[U4(bu + ud)],
            A2 = lds4[U4(bu + 2u * ud)], A3 = lds4[U4(bu + 3u * ud)];
      CSV(A0,A2,up) CSV(A1,A3,up)         // stride j
      CSV(A0,A1,up) CSV(A2,A3,up)         // stride j/2
      lds4[U4(bu)] = A0;           lds4[U4(bu + ud)] = A1;
      lds4[U4(bu + 2u * ud)] = A2; lds4[U4(bu + 3u * ud)] = A3;
    }
    j >>= 2;
  }
  if (j == 16u) {                         // single stride-16 round
    u32 total = Lw >> 3;                  // 8-elem instances
    for (u32 inst = lane; inst < total; inst += 64u) {
      u32 bu = RU + (((inst & ~3u) << 1) | (inst & 3u));
      bool up = (((gbase + (bu << 2)) & k) == 0u);
      uint4 A = lds4[U4(bu)], B = lds4[U4(bu + 4u)];
      CSV(A,B,up)
      lds4[U4(bu)] = A; lds4[U4(bu + 4u)] = B;
    }
  }
}

// ---- BLOCK-WIDE fused cross-wave trips (lower region, absolute directions).
__device__ __forceinline__ void cross1(uint4* lds4, u32 Wn, u32 gb, u32 k, u32 jtop, u32 tid)
{
  u32 ud = jtop >> 2;
  u32 total = Wn >> 3;
  for (u32 inst = tid; inst < total; inst += STH) {
    u32 bu = ((inst & ~(ud - 1u)) << 1) | (inst & (ud - 1u));
    bool up = (((gb + (bu << 2)) & k) == 0u);
    uint4 A = lds4[U4(bu)], B = lds4[U4(bu + ud)];
    CSV(A,B,up)
    lds4[U4(bu)] = A; lds4[U4(bu + ud)] = B;
  }
}
__device__ __forceinline__ void cross2(uint4* lds4, u32 Wn, u32 gb, u32 k, u32 jtop, u32 tid)
{
  u32 ud = jtop >> 3;
  u32 total = Wn >> 4;
  for (u32 inst = tid; inst < total; inst += STH) {
    u32 bu = ((inst & ~(ud - 1u)) << 2) | (inst & (ud - 1u));
    bool up = (((gb + (bu << 2)) & k) == 0u);
    uint4 A0 = lds4[U4(bu)],            A1 = lds4[U4(bu + ud)],
          A2 = lds4[U4(bu + 2u * ud)],  A3 = lds4[U4(bu + 3u * ud)];
    CSV(A0,A2,up) CSV(A1,A3,up)
    CSV(A0,A1,up) CSV(A2,A3,up)
    lds4[U4(bu)] = A0;           lds4[U4(bu + ud)] = A1;
    lds4[U4(bu + 2u * ud)] = A2; lds4[U4(bu + 3u * ud)] = A3;
  }
}
__device__ __forceinline__ void cross3(uint4* lds4, u32 Wn, u32 gb, u32 k, u32 jtop, u32 tid)
{
  u32 ud = jtop >> 4;
  u32 total = Wn >> 5;
  for (u32 inst = tid; inst < total; inst += STH) {
    u32 bu = ((inst & ~(ud - 1u)) << 3) | (inst & (ud - 1u));
    bool up = (((gb + (bu << 2)) & k) == 0u);
    uint4 A0 = lds4[U4(bu)],            A1 = lds4[U4(bu + ud)],
          A2 = lds4[U4(bu + 2u * ud)],  A3 = lds4[U4(bu + 3u * ud)],
          A4 = lds4[U4(bu + 4u * ud)],  A5 = lds4[U4(bu + 5u * ud)],
          A6 = lds4[U4(bu + 6u * ud)],  A7 = lds4[U4(bu + 7u * ud)];
    CSV(A0,A4,up) CSV(A1,A5,up) CSV(A2,A6,up) CSV(A3,A7,up)
    CSV(A0,A2,up) CSV(A1,A3,up) CSV(A4,A6,up) CSV(A5,A7,up)
    CSV(A0,A1,up) CSV(A2,A3,up) CSV(A4,A5,up) CSV(A6,A7,up)
    lds4[U4(bu)] = A0;           lds4[U4(bu + ud)] = A1;
    lds4[U4(bu + 2u * ud)] = A2; lds4[U4(bu + 3u * ud)] = A3;
    lds4[U4(bu + 4u * ud)] = A4; lds4[U4(bu + 5u * ud)] = A5;
    lds4[U4(bu + 6u * ud)] = A6; lds4[U4(bu + 7u * ud)] = A7;
  }
}

// ---- Upper-half (units +2048) cross trips with WINDOW-LOCAL directions.
__device__ __forceinline__ void crossB1(uint4* lds4, u32 Wn, u32 k, u32 jtop, u32 tid)
{
  u32 ud = jtop >> 2;
  u32 total = Wn >> 3;
  for (u32 inst = tid; inst < total; inst += STH) {
    u32 buL = ((inst & ~(ud - 1u)) << 1) | (inst & (ud - 1u));
    bool up = (((buL << 2) & k) == 0u);
    u32 bu = buL + 2048u;
    uint4 A = lds4[U4(bu)], B = lds4[U4(bu + ud)];
    CSV(A,B,up)
    lds4[U4(bu)] = A; lds4[U4(bu + ud)] = B;
  }
}
__device__ __forceinline__ void crossB2(uint4* lds4, u32 Wn, u32 k, u32 jtop, u32 tid)
{
  u32 ud = jtop >> 3;
  u32 total = Wn >> 4;
  for (u32 inst = tid; inst < total; inst += STH) {
    u32 buL = ((inst & ~(ud - 1u)) << 2) | (inst & (ud - 1u));
    bool up = (((buL << 2) & k) == 0u);
    u32 bu = buL + 2048u;
    uint4 A0 = lds4[U4(bu)],            A1 = lds4[U4(bu + ud)],
          A2 = lds4[U4(bu + 2u * ud)],  A3 = lds4[U4(bu + 3u * ud)];
    CSV(A0,A2,up) CSV(A1,A3,up)
    CSV(A0,A1,up) CSV(A2,A3,up)
    lds4[U4(bu)] = A0;           lds4[U4(bu + ud)] = A1;
    lds4[U4(bu + 2u * ud)] = A2; lds4[U4(bu + 3u * ud)] = A3;
  }
}
__device__ __forceinline__ void crossB3(uint4* lds4, u32 Wn, u32 k, u32 jtop, u32 tid)
{
  u32 ud = jtop >> 4;
  u32 total = Wn >> 5;
  for (u32 inst = tid; inst < total; inst += STH) {
    u32 buL = ((inst & ~(ud - 1u)) << 3) | (inst & (ud - 1u));
    bool up = (((buL << 2) & k) == 0u);
    u32 bu = buL + 2048u;
    uint4 A0 = lds4[U4(bu)],            A1 = lds4[U4(bu + ud)],
          A2 = lds4[U4(bu + 2u * ud)],  A3 = lds4[U4(bu + 3u * ud)],
          A4 = lds4[U4(bu + 4u * ud)],  A5 = lds4[U4(bu + 5u * ud)],
          A6 = lds4[U4(bu + 6u * ud)],  A7 = lds4[U4(bu + 7u * ud)];
    CSV(A0,A4,up) CSV(A1,A5,up) CSV(A2,A6,up) CSV(A3,A7,up)
    CSV(A0,A2,up) CSV(A1,A3,up) CSV(A4,A6,up) CSV(A5,A7,up)
    CSV(A0,A1,up) CSV(A2,A3,up) CSV(A4,A5,up) CSV(A6,A7,up)
    lds4[U4(bu)] = A0;           lds4[U4(bu + ud)] = A1;
    lds4[U4(bu + 2u * ud)] = A2; lds4[U4(bu + 3u * ud)] = A3;
    lds4[U4(bu + 4u * ud)] = A4; lds4[U4(bu + 5u * ud)] = A5;
    lds4[U4(bu + 6u * ud)] = A6; lds4[U4(bu + 7u * ud)] = A7;
  }
}

// ---------------- K1: cluster assign + softmax filling + per-block histograms
__global__ __launch_bounds__(256) void k_assign(
    const float* __restrict__ x, const float* __restrict__ centers,
    const int* __restrict__ predT, int* __restrict__ predX,
    float* __restrict__ fill_sum, u32* __restrict__ histX, u32* __restrict__ histT)
{
  __shared__ float c[KCL][DIMS];
  __shared__ float cn[KCL];
  __shared__ float fs[KCL];
  __shared__ u32 hx[KCL], ht[KCL];
  int tid = threadIdx.x;
  for (int t = tid; t < KCL * DIMS; t += 256) c[t / DIMS][t % DIMS] = centers[t];
  if (tid < KCL) { fs[tid] = 0.f; hx[tid] = 0; ht[tid] = 0; }
  __syncthreads();
  if (tid < KCL) {
    float s = 0.f;
    for (int d = 0; d < DIMS; ++d) s += c[tid][d] * c[tid][d];
    cn[tid] = s;
  }
  __syncthreads();
  int i = blockIdx.x * 256 + tid;
  const float4* xr = (const float4*)(x + (size_t)i * DIMS);
  float dot[KCL];
#pragma unroll
  for (int k = 0; k < KCL; ++k) dot[k] = 0.f;
  for (int t = 0; t < DIMS / 4; ++t) {
    float4 v = xr[t];
#pragma unroll
    for (int k = 0; k < KCL; ++k)
      dot[k] += v.x * c[k][4 * t] + v.y * c[k][4 * t + 1] + v.z * c[k][4 * t + 2] + v.w * c[k][4 * t + 3];
  }
  float sc[KCL];
  float smin = 3.0e38f; int kmin = 0;
#pragma unroll
  for (int k = 0; k < KCL; ++k) {
    sc[k] = cn[k] - 2.f * dot[k];
    if (sc[k] < smin) { smin = sc[k]; kmin = k; }
  }
  float e[KCL]; float esum = 0.f;
#pragma unroll
  for (int k = 0; k < KCL; ++k) { e[k] = expf(-BETA * (sc[k] - smin)); esum += e[k]; }
  float inv = 1.f / esum;
#pragma unroll
  for (int k = 0; k < KCL; ++k) atomicAdd(&fs[k], e[k] * inv);
  predX[i] = kmin;
  atomicAdd(&hx[kmin], 1u);
  atomicAdd(&ht[predT[i]], 1u);
  __syncthreads();
  if (tid < KCL) {
    histX[blockIdx.x * KCL + tid] = hx[tid];
    histT[blockIdx.x * KCL + tid] = ht[tid];
    atomicAdd(&fill_sum[tid], fs[tid]);
  }
}

// ---------------- K2: scan hists -> bases, totals, m, w, p, pOff, mOff, nlo, loss_fil
__global__ __launch_bounds__(512) void k_scan(
    const u32* __restrict__ histX, const u32* __restrict__ histT,
    u32* __restrict__ baseX, u32* __restrict__ baseT,
    const float* __restrict__ fill_sum, const float* __restrict__ ftarget,
    int* __restrict__ m_out, float* __restrict__ w_out,
    int* __restrict__ p_out, int* __restrict__ pOff_out, int* __restrict__ mOff_out,
    int* __restrict__ nlo_out, float* __restrict__ loss_fil)
{
  __shared__ u32 part[2][KCL][17];
  __shared__ u32 tot[2][KCL];
  __shared__ float sq[KCL];
  __shared__ int sp[KCL];
  __shared__ int smv[KCL];
  int tid = threadIdx.x;
  int side = tid >> 8;
  int rem = tid & 255;
  int c = rem >> 4;
  int sub = rem & 15;
  const u32* hist = side ? histT : histX;
  u32* base = side ? baseT : baseX;
  int b0 = sub * 32;
  u32 s = 0;
  for (int b = b0; b < b0 + 32; ++b) s += hist[b * KCL + c];
  part[side][c][sub] = s;
  __syncthreads();
  if (sub == 0) {
    u32 run = 0;
    for (int t = 0; t < 16; ++t) { u32 v = part[side][c][t]; part[side][c][t] = run; run += v; }
    tot[side][c] = run;
  }
  __syncthreads();
  u32 run = part[side][c][sub];
  for (int b = b0; b < b0 + 32; ++b) { base[b * KCL + c] = run; run += hist[b * KCL + c]; }
  if (tid < KCL) {
    int m = min((int)tot[0][tid], (int)tot[1][tid]);
    m_out[tid] = m;
    smv[tid] = m;
    w_out[tid] = (m > 0) ? 1.f / ((float)m * (float)DIMS) : 0.f;
    int pp = 32;
    while (pp < m) pp <<= 1;
    sp[tid] = pp;
    p_out[tid] = pp;
    // nlo = count of low (0x00) pads that sort to the FRONT of the cluster:
    //  - p > CHUNK: pads in descending (odd) 16K chunks (old rule)
    //  - p == CHUNK: dual-sub sort puts ALL pads (0x00, in sub1) at the front
    int nlo = 0;
    if (pp > CHUNK) {
      int nch = pp / CHUNK;
      for (int j = 1; j < nch; j += 2) {
        int v = m - j * CHUNK;
        if (v < 0) v = 0;
        if (v > CHUNK) v = CHUNK;
        nlo += CHUNK - v;
      }
    } else if (pp == CHUNK) {
      nlo = CHUNK - m;
    }
    nlo_out[tid] = nlo;
    float d = fill_sum[tid] / (float)N_ROWS - ftarget[tid];
    sq[tid] = d * d;
  }
  __syncthreads();
  if (tid == 0) {
    float s2 = 0.f;
    int acc = 0, macc = 0;
    for (int k = 0; k < KCL; ++k) {
      s2 += sq[k];
      pOff_out[k] = acc;
      acc += sp[k];
      mOff_out[k] = macc;
      macc += smv[k];
    }
    pOff_out[KCL] = acc;
    mOff_out[KCL] = macc;
    *loss_fil = s2 / (float)KCL;
  }
}

// ---------------- K3: ordered within-cluster rank -> compact inverse index
__global__ __launch_bounds__(256) void k_rank(
    const int* __restrict__ predX, const int* __restrict__ predT,
    const u32* __restrict__ baseX, const u32* __restrict__ baseT,
    const int* __restrict__ mG, const int* __restrict__ mOffG,
    int* __restrict__ idxX, int* __restrict__ idxT)
{
  __shared__ int wcX[4][KCL], wcT[4][KCL];
  __shared__ int smo[KCL], sm2[KCL];
  int tid = threadIdx.x;
  int lane = tid & 63, wave = tid >> 6;
  if (tid < KCL) { smo[tid] = mOffG[tid]; sm2[tid] = mG[tid]; }
  int i = blockIdx.x * 256 + tid;
  int kx = predX[i], kt = predT[i];
  u64 below = (1ull << lane) - 1ull;
  int lrX = 0, lrT = 0;
  for (int cc = 0; cc < KCL; ++cc) {
    u64 mx = __ballot(kx == cc);
    u64 mt = __ballot(kt == cc);
    if (kx == cc) lrX = __popcll(mx & below);
    if (kt == cc) lrT = __popcll(mt & below);
    if (lane == 0) { wcX[wave][cc] = __popcll(mx); wcT[wave][cc] = __popcll(mt); }
  }
  __syncthreads();
  int wbX = 0, wbT = 0;
  for (int w2 = 0; w2 < wave; ++w2) { wbX += wcX[w2][kx]; wbT += wcT[w2][kt]; }
  int rX = (int)baseX[blockIdx.x * KCL + kx] + wbX + lrX;
  int rT = (int)baseT[blockIdx.x * KCL + kt] + wbT + lrT;
  if (rX < sm2[kx]) idxX[smo[kx] + rX] = i;
  if (rT < sm2[kt]) idxT[smo[kt] + rT] = i;
}

// ---------------- K4: gather rows into cluster-partitioned dim planes + pads.
// Pad value rule: p > CHUNK -> old per-16K-chunk parity (0x00 odd, 0xFF even);
// p == CHUNK -> 0x00 (all pads live in sub1, sorted to cluster front);
// p < CHUNK -> 0xFF.
__global__ __launch_bounds__(256) void k_gather(
    const float* __restrict__ x, const float* __restrict__ tgt,
    const int* __restrict__ idxX, const int* __restrict__ idxT,
    const int* __restrict__ pOffG, const int* __restrict__ mOffG,
    const int* __restrict__ mG, const int* __restrict__ pG,
    u32* __restrict__ valX, u32* __restrict__ valT, int d0, int Dbc)
{
  __shared__ int spOff[KCL + 1];
  __shared__ int smo[KCL], sm2[KCL], sp2[KCL];
  __shared__ float pl[32][257];       // planes[d_local][pos_local], padded
  __shared__ int sRowX[256], sRowT[256];
  __shared__ u32 sPv[256];
  int tid = threadIdx.x;
  if (tid <= KCL) spOff[tid] = pOffG[tid];
  if (tid < KCL) { smo[tid] = mOffG[tid]; sm2[tid] = mG[tid]; sp2[tid] = pG[tid]; }
  __syncthreads();
  int pos = blockIdx.x * 256 + tid;
  bool inr = pos < spOff[KCL];
  int c = 0, rel = 0;
  bool vld = false;
  if (inr) {
#pragma unroll
    for (int cc = 1; cc < KCL; ++cc) c += (pos >= spOff[cc]) ? 1 : 0;
    rel = pos - spOff[c];
    vld = rel < sm2[c];
  }

  if (Dbc == 64) {
    int w = vld ? (smo[c] + rel) : 0;
    sRowX[tid] = vld ? idxX[w] : -1;
    sRowT[tid] = vld ? idxT[w] : -1;
    u32 pv = 0u;
    if (inr) {
      if (sp2[c] > CHUNK)       pv = ((rel >> 14) & 1) ? 0u : 0xFFFFFFFFu;
      else if (sp2[c] == CHUNK) pv = 0u;
      else                      pv = 0xFFFFFFFFu;
    }
    sPv[tid] = pv;
    __syncthreads();
#pragma unroll
    for (int side = 0; side < 2; ++side) {
      const float* src = side ? tgt : x;
      const int* sRow = side ? sRowT : sRowX;
      u32* dst = side ? valT : valX;
#pragma unroll
      for (int h = 0; h < 2; ++h) {
        int h0 = h * 32;
        for (int idx = tid; idx < 256 * 8; idx += 256) {
          int r = idx >> 3, f = idx & 7;
          int row = sRow[r];
          if (row >= 0) {
            float4 v = *(const float4*)(src + (size_t)row * DIMS + d0 + h0 + f * 4);
            pl[f * 4 + 0][r] = v.x;
            pl[f * 4 + 1][r] = v.y;
            pl[f * 4 + 2][r] = v.z;
            pl[f * 4 + 3][r] = v.w;
          }
        }
        __syncthreads();
        if (inr) {
          bool v2 = sRow[tid] >= 0;
          u32 pvv = sPv[tid];
          for (int dl = 0; dl < 32; ++dl) {
            u32 e = v2 ? enc_f(pl[dl][tid]) : pvv;
            dst[(size_t)(h0 + dl) * SEG_STRIDE + pos] = e;
          }
        }
        __syncthreads();
      }
    }
    return;
  }

  // ---- generic fallback (Dbc != 64)
  if (!inr) return;
  u32* dx = valX + pos;
  u32* dt = valT + pos;
  if (vld) {
    int w = smo[c] + rel;
    int iX = idxX[w], iT = idxT[w];
    const float* xr = x + (size_t)iX * DIMS + d0;
    const float* tr = tgt + (size_t)iT * DIMS + d0;
    for (int d = 0; d < Dbc; ++d) {
      dx[(size_t)d * SEG_STRIDE] = enc_f(xr[d]);
      dt[(size_t)d * SEG_STRIDE] = enc_f(tr[d]);
    }
  } else {
    u32 pv;
    if (sp2[c] > CHUNK)       pv = ((rel >> 14) & 1) ? 0u : 0xFFFFFFFFu;
    else if (sp2[c] == CHUNK) pv = 0u;
    else                      pv = 0xFFFFFFFFu;
    for (int d = 0; d < Dbc; ++d) {
      dx[(size_t)d * SEG_STRIDE] = pv;
      dt[(size_t)d * SEG_STRIDE] = pv;
    }
  }
}

// ---------------- K5: per-16K-chunk windowed bitonic sort.
// p < CHUNK : single window W = next_pow2(v) (old verified path).
// p == CHUNK: DUAL-SUB mode — sub0 = elements 0..8191 (fully valid, ascending),
//   sub1 = window WB = next_pow2(v-8192) at base 8192, sorted descending via
//   XOR-inverted keys (0x00 raw pads sort to its end); then the k=16384 merge
//   stage produces ascending with 0x00 pads at the FRONT (nlo = 16384 - m).
// p > CHUNK : per-chunk full W=16384 sort with chunk-parity inversion (old).
__global__ __launch_bounds__(STH, 8) void k_sort(
    u32* __restrict__ vbase, const int* __restrict__ pG, const int* __restrict__ pOffG,
    const int* __restrict__ mG)
{
  __shared__ __align__(16) u32 lds[CHUNK];
  uint4* lds4 = (uint4*)lds;
  int t = blockIdx.x, c = -1, sub = 0, acc = 0;
  for (int cc = 0; cc < KCL; ++cc) {
    int pc0 = pG[cc];
    int nc = (pc0 > CHUNK) ? (pc0 / CHUNK) : 1;
    if (t < acc + nc) { c = cc; sub = t - acc; break; }
    acc += nc;
  }
  if (c < 0) return;
  int pc = pG[c];
  u32 CH = (u32)min(pc, CHUNK);
  u32 gb = (u32)sub * (u32)CHUNK;
  int v = mG[c] - (int)gb;                 // valid elements in this chunk
  if (v > (int)CH) v = (int)CH;
  if (v <= 0) return;                      // all-pad chunk
  bool dual = (pc == CHUNK);               // implies v > 8192
  u32 W, WB = 0;
  if (dual) {
    W = (u32)CHUNK;
    u32 vt = (u32)v - 8192u;
    WB = 32u;
    while (WB < vt) WB <<= 1;              // <= 8192
  } else {
    W = 32u;
    while (W < (u32)v) W <<= 1;
    if (W > CH) W = CH;
  }
  bool desc = (pc > CHUNK) && (sub & 1);
  u32 inv = desc ? 0xFFFFFFFFu : 0u;       // dual: inv = 0
  u32* seg = vbase + (size_t)blockIdx.y * SEG_STRIDE + pOffG[c] + gb;
  uint4* gp4 = (uint4*)seg;
  u32 tid = threadIdx.x;
  u32 lane = tid & 63u;
  u32 wv = tid >> 6;
  u32 ub = tid << 2;            // first unit of this thread's 16-elem tile
  u32 bas = tid << 4;           // first element index (absolute in chunk)
  u32 RU = wv << 8;             // wave run base, units (absolute)
  // per-thread sub-window parameters
  u32 subBase = 0, IV = inv, Wl = W;
  if (dual) {
    if (wv < 8u) { subBase = 0u;    IV = 0u;          Wl = 8192u; }
    else         { subBase = 8192u; IV = 0xFFFFFFFFu; Wl = WB;    }
  }
  u32 el = bas - subBase;                  // window-local element index
  bool act = el < Wl;
  u32 runL = (wv << 10) - subBase;         // window-local run base
  bool wact = runL < Wl;
  u32 Lw = Wl - runL; if (Lw > 1024u) Lw = 1024u;
  u32 gAdj = 0u - subBase;                 // direction shift for wave_tail
  u32 r0,r1,r2,r3,r4,r5,r6,r7,r8,r9,r10,r11,r12,r13,r14,r15;

  // ---- Phase A: global -> regs, 16-sort, wave-local stages (no barriers)
  if (act) {
    uint4 a0 = gp4[ub + 0], a1 = gp4[ub + 1], a2 = gp4[ub + 2], a3 = gp4[ub + 3];
    r0 = a0.x^IV; r1 = a0.y^IV; r2  = a0.z^IV; r3  = a0.w^IV;
    r4 = a1.x^IV; r5 = a1.y^IV; r6  = a1.z^IV; r7  = a1.w^IV;
    r8 = a2.x^IV; r9 = a2.y^IV; r10 = a2.z^IV; r11 = a2.w^IV;
    r12 = a3.x^IV; r13 = a3.y^IV; r14 = a3.z^IV; r15 = a3.w^IV;
    bool D = ((el & 16u) == 0u);
    SORT16F(D);
    STORETILE16(lds4);
  } else if (dual) {
    // sub1 pad region: seed LDS with raw 0x00 pads (needed for full write-out)
    r0=0;r1=0;r2=0;r3=0;r4=0;r5=0;r6=0;r7=0;r8=0;r9=0;r10=0;r11=0;r12=0;r13=0;r14=0;r15=0;
    STORETILE16(lds4);
  }
  if (wact) {
    for (u32 k = 32u; k <= Lw; k <<= 1) {
      wave_tail(lds4, RU, Lw, gAdj, k, k >> 1, lane);
      if (act) {
        LOADTILE16(lds4);
        bool D = ((el & k) == 0u);
        MERGE16F(D);
        STORETILE16(lds4);
      }
    }
  }

  // ---- sub1 cross-wave stages (dual, WB >= 2048) — rare (m > 9216)
  if (dual && WB >= 2048u) {
    __syncthreads();
    for (u32 k = 2048u; k <= WB; k <<= 1) {
      u32 jt = k >> 1;
      if (jt == 4096u) crossB3(lds4, WB, k, 4096u, tid);
      else if (jt == 2048u) crossB2(lds4, WB, k, 2048u, tid);
      else crossB1(lds4, WB, k, 1024u, tid);
      __syncthreads();
      if (wv >= 8u && wact) {
        wave_tail(lds4, RU, Lw, gAdj, k, 512u, lane);
        if (act) {
          LOADTILE16(lds4);
          bool D = ((el & k) == 0u);
          MERGE16F(D);
          STORETILE16(lds4);
        }
      }
      __syncthreads();
    }
  }
  // ---- de-transform sub1 to raw (wave-local, no barrier needed)
  if (dual && wv >= 8u && act) {
    LOADTILE16(lds4);
    r0^=IV; r1^=IV; r2^=IV; r3^=IV; r4^=IV; r5^=IV; r6^=IV; r7^=IV;
    r8^=IV; r9^=IV; r10^=IV; r11^=IV; r12^=IV; r13^=IV; r14^=IV; r15^=IV;
    STORETILE16(lds4);
  }

  // ---- main Phase B: k = 2048..W
  // dual: k<=8192 stages confined to sub0 (lower half); k=16384 = full merge.
  if (W >= 2048u) {
    __syncthreads();
    for (u32 k = 2048u; k <= W; k <<= 1) {
      u32 jt = k >> 1;
      u32 Wc = dual ? ((k == (u32)CHUNK) ? (u32)CHUNK : 8192u) : W;
      if (jt >= 8192u) {                  // k = 16384: strides 8192..1024
        cross3(lds4, Wc, 0u, k, 8192u, tid);
        __syncthreads();
        cross1(lds4, Wc, 0u, k, 1024u, tid);
        __syncthreads();
      } else if (jt == 4096u) {
        cross3(lds4, Wc, 0u, k, 4096u, tid);
        __syncthreads();
      } else if (jt == 2048u) {
        cross2(lds4, Wc, 0u, k, 2048u, tid);
        __syncthreads();
      } else {
        cross1(lds4, Wc, 0u, k, 1024u, tid);
        __syncthreads();
      }
      bool part = dual ? ((k == (u32)CHUNK) ? true : (wv < 8u)) : wact;
      u32 LwT = dual ? 1024u : Lw;
      if (part) {
        wave_tail(lds4, RU, LwT, 0u, k, 512u, lane);
        bool mact = dual ? ((k == (u32)CHUNK) ? true : (bas < 8192u)) : act;
        if (mact) {
          LOADTILE16(lds4);
          bool D = ((bas & k) == 0u);
          MERGE16F(D);
          STORETILE16(lds4);
        }
      }
      if (k < W) __syncthreads();
    }
  }

  // ---- lane-striped dense write-out (full cache lines)
  __syncthreads();
  for (u32 uu = tid; (uu << 2) < W; uu += STH) {
    uint4 q = lds4[U4(uu)];
    q.x ^= inv; q.y ^= inv; q.z ^= inv; q.w ^= inv;
    gp4[uu] = q;
  }
}

// ---------------- K6: global bitonic pass for big segments (j >= CHUNK).
__global__ __launch_bounds__(256) void k_gpass(
    u32* __restrict__ vbase, const int* __restrict__ pG, const int* __restrict__ pOffG,
    int kk, int j)
{
  u32* base = vbase + (size_t)blockIdx.y * SEG_STRIDE;
  int pb[KCL]; int tot = 0;
#pragma unroll
  for (int c = 0; c < KCL; ++c) {
    pb[c] = tot;
    int pc = pG[c];
    if (pc >= kk) tot += pc >> 1;
  }
  for (int g4 = (blockIdx.x * 256 + threadIdx.x) << 2; g4 < tot; g4 += gridDim.x * 256 * 4) {
    int c = 0;
#pragma unroll
    for (int cc = 1; cc < KCL; ++cc) c += (g4 >= pb[cc]) ? 1 : 0;
    int u = g4 - pb[c];
    int i = ((u & ~(j - 1)) << 1) | (u & (j - 1));
    bool up = ((i & kk) == 0);
    u32* s2 = base + pOffG[c];
    uint4 A = *(const uint4*)(s2 + i);
    uint4 B = *(const uint4*)(s2 + i + j);
    CS(A.x, B.x, up) CS(A.y, B.y, up) CS(A.z, B.z, up) CS(A.w, B.w, up)
    *(uint4*)(s2 + i) = A;
    *(uint4*)(s2 + i + j) = B;
  }
}

// ---------------- K7: finish big-segment stage (strides <= 8192) in 64KB LDS.
__global__ __launch_bounds__(STH) void k_gfinish(
    u32* __restrict__ vbase, const int* __restrict__ pG, const int* __restrict__ pOffG, int kk)
{
  __shared__ __align__(16) u32 lds[CHUNK];
  uint4* lds4 = (uint4*)lds;
  int t = blockIdx.x, c = -1, sub = 0, acc = 0;
  for (int cc = 0; cc < KCL; ++cc) {
    int pc = pG[cc];
    if (pc < kk) continue;
    int nc = pc / CHUNK;
    if (t < acc + nc) { c = cc; sub = t - acc; break; }
    acc += nc;
  }
  if (c < 0) return;
  u32 gb = (u32)sub * (u32)CHUNK;
  u32* seg = vbase + (size_t)blockIdx.y * SEG_STRIDE + pOffG[c] + gb;
  uint4* gp4 = (uint4*)seg;
  u32 tid = threadIdx.x;
  u32 lane = tid & 63u;
  u32 wv = tid >> 6;
  u32 RU = wv << 8;
  u32 ub = tid << 2;
  u32 bas = tid << 4;
  u32 r0,r1,r2,r3,r4,r5,r6,r7,r8,r9,r10,r11,r12,r13,r14,r15;

  for (u32 uu = tid; uu < CHUNK / 4; uu += STH) lds4[U4(uu)] = gp4[uu];
  __syncthreads();
  cross3(lds4, (u32)CHUNK, gb, (u32)kk, 8192u, tid);   // strides 8192..2048
  __syncthreads();
  cross1(lds4, (u32)CHUNK, gb, (u32)kk, 1024u, tid);   // stride 1024
  __syncthreads();
  wave_tail(lds4, RU, 1024u, gb, (u32)kk, 512u, lane); // strides 512..16
  {
    LOADTILE16(lds4);
    bool up = (((gb + bas) & (u32)kk) == 0u);
    MERGE16F(up);
    STORETILE16(lds4);
  }
  __syncthreads();
  for (u32 uu = tid; uu < CHUNK / 4; uu += STH) gp4[uu] = lds4[U4(uu)];
}

// ---------------- K8: windowed |diff| reduce over valid positions only.
// Valid window per cluster = [pOff + nlo, pOff + nlo + m).
__global__ __launch_bounds__(256) void k_reduce(
    const u32* __restrict__ valX, const u32* __restrict__ valT,
    const int* __restrict__ pOffG, const int* __restrict__ mOffG,
    const int* __restrict__ nloG,
    const float* __restrict__ wG, float* __restrict__ lossAcc)
{
  __shared__ int spOff[KCL];
  __shared__ int smo[KCL + 1];
  __shared__ int snlo[KCL];
  __shared__ float swt[KCL];
  __shared__ float red[256];
  int tid = threadIdx.x;
  if (tid <= KCL) smo[tid] = mOffG[tid];
  if (tid < KCL) { spOff[tid] = pOffG[tid]; snlo[tid] = nloG[tid]; swt[tid] = wG[tid]; }
  __syncthreads();
  int d = blockIdx.y;
  const u32* vx = valX + (size_t)d * SEG_STRIDE;
  const u32* vt = valT + (size_t)d * SEG_STRIDE;
  int M = smo[KCL];
  float s = 0.f;
  for (int w = blockIdx.x * 256 + tid; w < M; w += gridDim.x * 256) {
    int c = 0;
#pragma unroll
    for (int cc = 1; cc < KCL; ++cc) c += (w >= smo[cc]) ? 1 : 0;
    int pos = spOff[c] + snlo[c] + (w - smo[c]);
    float a = dec_f(vx[pos]), b = dec_f(vt[pos]);
    s += fabsf(a - b) * swt[c];
  }
  red[tid] = s;
  __syncthreads();
  for (int st = 128; st > 0; st >>= 1) {
    if (tid < st) red[tid] += red[tid + st];
    __syncthreads();
  }
  if (tid == 0) atomicAdd(lossAcc, red[0]);
}

// ---------------- K9: final scalar
__global__ void k_final(const float* __restrict__ lossAcc, const float* __restrict__ loss_fil,
                        float* __restrict__ out)
{
  out[0] = *lossAcc + *loss_fil;
}

extern "C" void kernel_launch(void* const* d_in, const int* in_sizes, int n_in,
                              void* d_out, int out_size, void* d_ws, size_t ws_size,
                              hipStream_t stream)
{
  const float* x       = (const float*)d_in[0];
  const float* centers = (const float*)d_in[1];
  const float* ftarget = (const float*)d_in[2];
  const float* tgt     = (const float*)d_in[3];
  const int*   predT   = (const int*)d_in[4];
  float* out = (float*)d_out;

  char* ws = (char*)d_ws;
  float* fill_sum = (float*)(ws + 0);       // 16 f (zeroed)
  float* lossAcc  = (float*)(ws + 64);      // zeroed
  float* loss_fil = (float*)(ws + 68);      // zeroed
  int*   m_buf    = (int*)(ws + 128);
  float* w_buf    = (float*)(ws + 192);
  int*   p_buf    = (int*)(ws + 256);
  int*   pOff     = (int*)(ws + 320);       // 17 ints
  int*   mOff     = (int*)(ws + 400);       // 17 ints
  u32* histX = (u32*)(ws + 512);            // 512*16*4 = 32768
  u32* histT = (u32*)(ws + 512 + 32768);
  u32* baseX = (u32*)(ws + 512 + 65536);
  u32* baseT = (u32*)(ws + 512 + 98304);
  int* predX = (int*)(ws + 131584);         // 524288
  int* idxX  = (int*)(ws + 655872);         // 524288 (compact, Sum(m) <= 131072)
  int* idxT  = (int*)(ws + 1180160);        // 524288
  int* nlo_buf = (int*)(ws + 1704448);      // 16 ints
  u32* vbase = (u32*)(ws + VOFF);

  size_t avail_elems = (ws_size > VOFF) ? ((ws_size - VOFF) / 4) : 0;
  int Db = (int)(avail_elems / (2ull * SEG_STRIDE));
  if (Db > DIMS) Db = DIMS;
  if (Db >= 4) Db &= ~3;
  if (Db < 1) Db = 1;

  hipMemsetAsync(ws, 0, 128, stream);
  k_assign<<<NBLK, 256, 0, stream>>>(x, centers, predT, predX, fill_sum, histX, histT);
  k_scan<<<1, 512, 0, stream>>>(histX, histT, baseX, baseT, fill_sum, ftarget,
                                m_buf, w_buf, p_buf, pOff, mOff, nlo_buf, loss_fil);
  k_rank<<<NBLK, 256, 0, stream>>>(predX, predT, baseX, baseT, m_buf, mOff, idxX, idxT);

  for (int d0 = 0; d0 < DIMS; d0 += Db) {
    int Dbc = (Db < DIMS - d0) ? Db : (DIMS - d0);
    u32* valX = vbase;
    u32* valT = vbase + (size_t)Dbc * SEG_STRIDE;
    // 1028 * 256 = 263168 >= worst-case Sum(p); values + pads in one pass
    k_gather<<<1028, 256, 0, stream>>>(x, tgt, idxX, idxT, pOff, mOff, m_buf, p_buf,
                                       valX, valT, d0, Dbc);
    // worst-case chunk count: Sum max(1, p/16384) <= 26 -> 28 x-blocks (extras exit)
    k_sort<<<dim3(28, 2 * Dbc), STH, 0, stream>>>(vbase, p_buf, pOff, m_buf);
    // parallel merge stages for clusters with p > 16384 (early-exit when none)
    for (int kk = 2 * CHUNK; kk <= N_ROWS; kk <<= 1) {
      int gx = (kk == 2 * CHUNK) ? 32 : 8;
      for (int j = kk >> 1; j >= CHUNK; j >>= 1)
        k_gpass<<<dim3(gx, 2 * Dbc), 256, 0, stream>>>(vbase, p_buf, pOff, kk, j);
      k_gfinish<<<dim3(18, 2 * Dbc), STH, 0, stream>>>(vbase, p_buf, pOff, kk);
    }
    k_reduce<<<dim3(32, Dbc), 256, 0, stream>>>(valX, valT, pOff, mOff, nlo_buf,
                                                w_buf, lossAcc);
  }
  k_final<<<1, 1, 0, stream>>>(lossAcc, loss_fil, out);
}

// Round 13
// 604.079 us; speedup vs baseline: 1.0290x; 1.0125x over previous
//
#include <hip/hip_runtime.h>
#include <stdint.h>

#define N_ROWS 131072
#define DIMS 64
#define KCL 16
#define BETA 4.0f
#define NBLK 512            // N_ROWS / 256
#define CHUNK 16384         // elements per LDS sort chunk (16384 * 4B = 64KB LDS)
#define STH 1024            // sort threads per block (16 waves)
#define SEG_STRIDE 263168   // u32 elements per (dim,side)
#define VOFF (1u<<21)

typedef unsigned long long u64;
typedef unsigned int u32;

__device__ __forceinline__ u32 enc_f(float f) {
  u32 u = __float_as_uint(f);
  return (u & 0x80000000u) ? ~u : (u | 0x80000000u);
}
__device__ __forceinline__ float dec_f(u32 e) {
  u32 u = (e & 0x80000000u) ? (e & 0x7FFFFFFFu) : ~e;
  return __uint_as_float(u);
}
// unit (uint4) granularity bank swizzle
__device__ __forceinline__ u32 U4(u32 u) { return u ^ ((u >> 3) & 7u); }

#define CS(a,b,dd) { u32 _mn = min(a,b), _mx = max(a,b); a = (dd)?_mn:_mx; b = (dd)?_mx:_mn; }
#define CSV(A,B,D) { CS(A.x,B.x,D) CS(A.y,B.y,D) CS(A.z,B.z,D) CS(A.w,B.w,D) }

// bitonic merge of 16 named regs, direction D (strides 8,4,2,1)
#define M16G(a,b,c,d,e,f,g,h,i2,j2,k2,l,m,n,o,p,D) \
  CS(a,i2,D) CS(b,j2,D) CS(c,k2,D) CS(d,l,D) CS(e,m,D) CS(f,n,D) CS(g,o,D) CS(h,p,D) \
  CS(a,e,D)  CS(b,f,D)  CS(c,g,D)  CS(d,h,D) CS(i2,m,D) CS(j2,n,D) CS(k2,o,D) CS(l,p,D) \
  CS(a,c,D)  CS(b,d,D)  CS(e,g,D)  CS(f,h,D) CS(i2,k2,D) CS(j2,l,D) CS(m,o,D) CS(n,p,D) \
  CS(a,b,D)  CS(c,d,D)  CS(e,f,D)  CS(g,h,D) CS(i2,j2,D) CS(k2,l,D) CS(m,n,D) CS(o,p,D)

// full bitonic sort of 16 named regs with final direction D
#define SORT16G(a,b,c,d,e,f,g,h,i2,j2,k2,l,m,n,o,p,D) \
  CS(a,b,D) CS(c,d,!(D)) CS(e,f,D) CS(g,h,!(D)) CS(i2,j2,D) CS(k2,l,!(D)) CS(m,n,D) CS(o,p,!(D)) \
  CS(a,c,D) CS(b,d,D) CS(e,g,!(D)) CS(f,h,!(D)) CS(i2,k2,D) CS(j2,l,D) CS(m,o,!(D)) CS(n,p,!(D)) \
  CS(a,b,D) CS(c,d,D) CS(e,f,!(D)) CS(g,h,!(D)) CS(i2,j2,D) CS(k2,l,D) CS(m,n,!(D)) CS(o,p,!(D)) \
  CS(a,e,D) CS(b,f,D) CS(c,g,D) CS(d,h,D) CS(i2,m,!(D)) CS(j2,n,!(D)) CS(k2,o,!(D)) CS(l,p,!(D)) \
  CS(a,c,D) CS(b,d,D) CS(e,g,D) CS(f,h,D) CS(i2,k2,!(D)) CS(j2,l,!(D)) CS(m,o,!(D)) CS(n,p,!(D)) \
  CS(a,b,D) CS(c,d,D) CS(e,f,D) CS(g,h,D) CS(i2,j2,!(D)) CS(k2,l,!(D)) CS(m,n,!(D)) CS(o,p,!(D)) \
  M16G(a,b,c,d,e,f,g,h,i2,j2,k2,l,m,n,o,p,D)

#define MERGE16F(D) M16G(r0,r1,r2,r3,r4,r5,r6,r7,r8,r9,r10,r11,r12,r13,r14,r15,D)
#define SORT16F(D)  SORT16G(r0,r1,r2,r3,r4,r5,r6,r7,r8,r9,r10,r11,r12,r13,r14,r15,D)

#define LOADTILE16(src) \
  { uint4 _a0=src[U4(ub+0)],_a1=src[U4(ub+1)],_a2=src[U4(ub+2)],_a3=src[U4(ub+3)]; \
    r0=_a0.x;r1=_a0.y;r2=_a0.z;r3=_a0.w; r4=_a1.x;r5=_a1.y;r6=_a1.z;r7=_a1.w; \
    r8=_a2.x;r9=_a2.y;r10=_a2.z;r11=_a2.w; r12=_a3.x;r13=_a3.y;r14=_a3.z;r15=_a3.w; }

#define STORETILE16(dst) \
  { dst[U4(ub+0)]=make_uint4(r0,r1,r2,r3);   dst[U4(ub+1)]=make_uint4(r4,r5,r6,r7); \
    dst[U4(ub+2)]=make_uint4(r8,r9,r10,r11); dst[U4(ub+3)]=make_uint4(r12,r13,r14,r15); }

// ---- WAVE-LOCAL bitonic rounds: strides jtop..16 within this wave's 1024-run.
// DS ops of one wave execute in program order on CDNA -> no barriers needed.
// 2-fused trips {j, j/2} with ALL 64 lanes active (16-elem instances).
__device__ __forceinline__ void wave_tail(uint4* lds4, u32 RU, u32 Lw, u32 gbase,
                                          u32 k, u32 jtop, u32 lane)
{
  u32 j = jtop;
  while (j >= 32u) {
    u32 ud = j >> 3;                      // units between the 4 loads (= j/2 elems)
    if (lane < (Lw >> 4)) {               // 16-elem instances
      u32 bu = RU + (((lane & ~(ud - 1u)) << 2) | (lane & (ud - 1u)));
      bool up = (((gbase + (bu << 2)) & k) == 0u);
      uint4 A0 = lds4[U4(bu)],           A1 = lds4[U4(bu + ud)],
            A2 = lds4[U4(bu + 2u * ud)], A3 = lds4[U4(bu + 3u * ud)];
      CSV(A0,A2,up) CSV(A1,A3,up)         // stride j
      CSV(A0,A1,up) CSV(A2,A3,up)         // stride j/2
      lds4[U4(bu)] = A0;           lds4[U4(bu + ud)] = A1;
      lds4[U4(bu + 2u * ud)] = A2; lds4[U4(bu + 3u * ud)] = A3;
    }
    j >>= 2;
  }
  if (j == 16u) {                         // single stride-16 round
    u32 total = Lw >> 3;                  // 8-elem instances
    for (u32 inst = lane; inst < total; inst += 64u) {
      u32 bu = RU + (((inst & ~3u) << 1) | (inst & 3u));
      bool up = (((gbase + (bu << 2)) & k) == 0u);
      uint4 A = lds4[U4(bu)], B = lds4[U4(bu + 4u)];
      CSV(A,B,up)
      lds4[U4(bu)] = A; lds4[U4(bu + 4u)] = B;
    }
  }
}

// ---- BLOCK-WIDE fused cross-wave trips.
__device__ __forceinline__ void cross1(uint4* lds4, u32 Wn, u32 gb, u32 k, u32 jtop, u32 tid)
{
  u32 ud = jtop >> 2;
  u32 total = Wn >> 3;
  for (u32 inst = tid; inst < total; inst += STH) {
    u32 bu = ((inst & ~(ud - 1u)) << 1) | (inst & (ud - 1u));
    bool up = (((gb + (bu << 2)) & k) == 0u);
    uint4 A = lds4[U4(bu)], B = lds4[U4(bu + ud)];
    CSV(A,B,up)
    lds4[U4(bu)] = A; lds4[U4(bu + ud)] = B;
  }
}
__device__ __forceinline__ void cross2(uint4* lds4, u32 Wn, u32 gb, u32 k, u32 jtop, u32 tid)
{
  u32 ud = jtop >> 3;
  u32 total = Wn >> 4;
  for (u32 inst = tid; inst < total; inst += STH) {
    u32 bu = ((inst & ~(ud - 1u)) << 2) | (inst & (ud - 1u));
    bool up = (((gb + (bu << 2)) & k) == 0u);
    uint4 A0 = lds4[U4(bu)],            A1 = lds4[U4(bu + ud)],
          A2 = lds4[U4(bu + 2u * ud)],  A3 = lds4[U4(bu + 3u * ud)];
    CSV(A0,A2,up) CSV(A1,A3,up)
    CSV(A0,A1,up) CSV(A2,A3,up)
    lds4[U4(bu)] = A0;           lds4[U4(bu + ud)] = A1;
    lds4[U4(bu + 2u * ud)] = A2; lds4[U4(bu + 3u * ud)] = A3;
  }
}
__device__ __forceinline__ void cross3(uint4* lds4, u32 Wn, u32 gb, u32 k, u32 jtop, u32 tid)
{
  u32 ud = jtop >> 4;
  u32 total = Wn >> 5;
  for (u32 inst = tid; inst < total; inst += STH) {
    u32 bu = ((inst & ~(ud - 1u)) << 3) | (inst & (ud - 1u));
    bool up = (((gb + (bu << 2)) & k) == 0u);
    uint4 A0 = lds4[U4(bu)],            A1 = lds4[U4(bu + ud)],
          A2 = lds4[U4(bu + 2u * ud)],  A3 = lds4[U4(bu + 3u * ud)],
          A4 = lds4[U4(bu + 4u * ud)],  A5 = lds4[U4(bu + 5u * ud)],
          A6 = lds4[U4(bu + 6u * ud)],  A7 = lds4[U4(bu + 7u * ud)];
    CSV(A0,A4,up) CSV(A1,A5,up) CSV(A2,A6,up) CSV(A3,A7,up)
    CSV(A0,A2,up) CSV(A1,A3,up) CSV(A4,A6,up) CSV(A5,A7,up)
    CSV(A0,A1,up) CSV(A2,A3,up) CSV(A4,A5,up) CSV(A6,A7,up)
    lds4[U4(bu)] = A0;           lds4[U4(bu + ud)] = A1;
    lds4[U4(bu + 2u * ud)] = A2; lds4[U4(bu + 3u * ud)] = A3;
    lds4[U4(bu + 4u * ud)] = A4; lds4[U4(bu + 5u * ud)] = A5;
    lds4[U4(bu + 6u * ud)] = A6; lds4[U4(bu + 7u * ud)] = A7;
  }
}

// ---------------- K1: cluster assign + softmax filling + per-block histograms
__global__ __launch_bounds__(256) void k_assign(
    const float* __restrict__ x, const float* __restrict__ centers,
    const int* __restrict__ predT, int* __restrict__ predX,
    float* __restrict__ fill_sum, u32* __restrict__ histX, u32* __restrict__ histT)
{
  __shared__ float c[KCL][DIMS];
  __shared__ float cn[KCL];
  __shared__ float fs[KCL];
  __shared__ u32 hx[KCL], ht[KCL];
  int tid = threadIdx.x;
  for (int t = tid; t < KCL * DIMS; t += 256) c[t / DIMS][t % DIMS] = centers[t];
  if (tid < KCL) { fs[tid] = 0.f; hx[tid] = 0; ht[tid] = 0; }
  __syncthreads();
  if (tid < KCL) {
    float s = 0.f;
    for (int d = 0; d < DIMS; ++d) s += c[tid][d] * c[tid][d];
    cn[tid] = s;
  }
  __syncthreads();
  int i = blockIdx.x * 256 + tid;
  const float4* xr = (const float4*)(x + (size_t)i * DIMS);
  float dot[KCL];
#pragma unroll
  for (int k = 0; k < KCL; ++k) dot[k] = 0.f;
  for (int t = 0; t < DIMS / 4; ++t) {
    float4 v = xr[t];
#pragma unroll
    for (int k = 0; k < KCL; ++k)
      dot[k] += v.x * c[k][4 * t] + v.y * c[k][4 * t + 1] + v.z * c[k][4 * t + 2] + v.w * c[k][4 * t + 3];
  }
  float sc[KCL];
  float smin = 3.0e38f; int kmin = 0;
#pragma unroll
  for (int k = 0; k < KCL; ++k) {
    sc[k] = cn[k] - 2.f * dot[k];
    if (sc[k] < smin) { smin = sc[k]; kmin = k; }
  }
  float e[KCL]; float esum = 0.f;
#pragma unroll
  for (int k = 0; k < KCL; ++k) { e[k] = expf(-BETA * (sc[k] - smin)); esum += e[k]; }
  float inv = 1.f / esum;
#pragma unroll
  for (int k = 0; k < KCL; ++k) atomicAdd(&fs[k], e[k] * inv);
  predX[i] = kmin;
  atomicAdd(&hx[kmin], 1u);
  atomicAdd(&ht[predT[i]], 1u);
  __syncthreads();
  if (tid < KCL) {
    histX[blockIdx.x * KCL + tid] = hx[tid];
    histT[blockIdx.x * KCL + tid] = ht[tid];
    atomicAdd(&fill_sum[tid], fs[tid]);
  }
}

// ---------------- K2: scan hists -> bases, totals, m, w, p, pOff, mOff, nlo, loss_fil
__global__ __launch_bounds__(512) void k_scan(
    const u32* __restrict__ histX, const u32* __restrict__ histT,
    u32* __restrict__ baseX, u32* __restrict__ baseT,
    const float* __restrict__ fill_sum, const float* __restrict__ ftarget,
    int* __restrict__ m_out, float* __restrict__ w_out,
    int* __restrict__ p_out, int* __restrict__ pOff_out, int* __restrict__ mOff_out,
    int* __restrict__ nlo_out, float* __restrict__ loss_fil)
{
  __shared__ u32 part[2][KCL][17];
  __shared__ u32 tot[2][KCL];
  __shared__ float sq[KCL];
  __shared__ int sp[KCL];
  __shared__ int smv[KCL];
  int tid = threadIdx.x;
  int side = tid >> 8;
  int rem = tid & 255;
  int c = rem >> 4;
  int sub = rem & 15;
  const u32* hist = side ? histT : histX;
  u32* base = side ? baseT : baseX;
  int b0 = sub * 32;
  u32 s = 0;
  for (int b = b0; b < b0 + 32; ++b) s += hist[b * KCL + c];
  part[side][c][sub] = s;
  __syncthreads();
  if (sub == 0) {
    u32 run = 0;
    for (int t = 0; t < 16; ++t) { u32 v = part[side][c][t]; part[side][c][t] = run; run += v; }
    tot[side][c] = run;
  }
  __syncthreads();
  u32 run = part[side][c][sub];
  for (int b = b0; b < b0 + 32; ++b) { base[b * KCL + c] = run; run += hist[b * KCL + c]; }
  if (tid < KCL) {
    int m = min((int)tot[0][tid], (int)tot[1][tid]);
    m_out[tid] = m;
    smv[tid] = m;
    w_out[tid] = (m > 0) ? 1.f / ((float)m * (float)DIMS) : 0.f;
    int pp = 32;
    while (pp < m) pp <<= 1;
    sp[tid] = pp;
    p_out[tid] = pp;
    // nlo = pads residing in descending (odd) 16K chunks -> land at segment FRONT
    // after the full ascending merge; valid window is [nlo, nlo+m).
    int nlo = 0;
    if (pp > CHUNK) {
      int nch = pp / CHUNK;
      for (int j = 1; j < nch; j += 2) {
        int v = m - j * CHUNK;
        if (v < 0) v = 0;
        if (v > CHUNK) v = CHUNK;
        nlo += CHUNK - v;
      }
    }
    nlo_out[tid] = nlo;
    float d = fill_sum[tid] / (float)N_ROWS - ftarget[tid];
    sq[tid] = d * d;
  }
  __syncthreads();
  if (tid == 0) {
    float s2 = 0.f;
    int acc = 0, macc = 0;
    for (int k = 0; k < KCL; ++k) {
      s2 += sq[k];
      pOff_out[k] = acc;
      acc += sp[k];
      mOff_out[k] = macc;
      macc += smv[k];
    }
    pOff_out[KCL] = acc;
    mOff_out[KCL] = macc;
    *loss_fil = s2 / (float)KCL;
  }
}

// ---------------- K3: ordered within-cluster rank -> compact inverse index
__global__ __launch_bounds__(256) void k_rank(
    const int* __restrict__ predX, const int* __restrict__ predT,
    const u32* __restrict__ baseX, const u32* __restrict__ baseT,
    const int* __restrict__ mG, const int* __restrict__ mOffG,
    int* __restrict__ idxX, int* __restrict__ idxT)
{
  __shared__ int wcX[4][KCL], wcT[4][KCL];
  __shared__ int smo[KCL], sm2[KCL];
  int tid = threadIdx.x;
  int lane = tid & 63, wave = tid >> 6;
  if (tid < KCL) { smo[tid] = mOffG[tid]; sm2[tid] = mG[tid]; }
  int i = blockIdx.x * 256 + tid;
  int kx = predX[i], kt = predT[i];
  u64 below = (1ull << lane) - 1ull;
  int lrX = 0, lrT = 0;
  for (int cc = 0; cc < KCL; ++cc) {
    u64 mx = __ballot(kx == cc);
    u64 mt = __ballot(kt == cc);
    if (kx == cc) lrX = __popcll(mx & below);
    if (kt == cc) lrT = __popcll(mt & below);
    if (lane == 0) { wcX[wave][cc] = __popcll(mx); wcT[wave][cc] = __popcll(mt); }
  }
  __syncthreads();
  int wbX = 0, wbT = 0;
  for (int w2 = 0; w2 < wave; ++w2) { wbX += wcX[w2][kx]; wbT += wcT[w2][kt]; }
  int rX = (int)baseX[blockIdx.x * KCL + kx] + wbX + lrX;
  int rT = (int)baseT[blockIdx.x * KCL + kt] + wbT + lrT;
  if (rX < sm2[kx]) idxX[smo[kx] + rX] = i;
  if (rT < sm2[kt]) idxT[smo[kt] + rT] = i;
}

// ---------------- K4: gather rows into cluster-partitioned dim planes + pads.
// Coalesced row loads transposed through LDS (round-8 verified form).
__global__ __launch_bounds__(256) void k_gather(
    const float* __restrict__ x, const float* __restrict__ tgt,
    const int* __restrict__ idxX, const int* __restrict__ idxT,
    const int* __restrict__ pOffG, const int* __restrict__ mOffG,
    const int* __restrict__ mG, const int* __restrict__ pG,
    u32* __restrict__ valX, u32* __restrict__ valT, int d0, int Dbc)
{
  __shared__ int spOff[KCL + 1];
  __shared__ int smo[KCL], sm2[KCL], sp2[KCL];
  __shared__ float pl[32][257];       // planes[d_local][pos_local], padded
  __shared__ int sRowX[256], sRowT[256];
  __shared__ u32 sPv[256];
  int tid = threadIdx.x;
  if (tid <= KCL) spOff[tid] = pOffG[tid];
  if (tid < KCL) { smo[tid] = mOffG[tid]; sm2[tid] = mG[tid]; sp2[tid] = pG[tid]; }
  __syncthreads();
  int pos = blockIdx.x * 256 + tid;
  bool inr = pos < spOff[KCL];
  int c = 0, rel = 0;
  bool vld = false;
  if (inr) {
#pragma unroll
    for (int cc = 1; cc < KCL; ++cc) c += (pos >= spOff[cc]) ? 1 : 0;
    rel = pos - spOff[c];
    vld = rel < sm2[c];
  }

  if (Dbc == 64) {
    int w = vld ? (smo[c] + rel) : 0;
    sRowX[tid] = vld ? idxX[w] : -1;
    sRowT[tid] = vld ? idxT[w] : -1;
    sPv[tid] = inr ? ((sp2[c] > CHUNK && ((rel >> 14) & 1)) ? 0u : 0xFFFFFFFFu) : 0u;
    __syncthreads();
#pragma unroll
    for (int side = 0; side < 2; ++side) {
      const float* src = side ? tgt : x;
      const int* sRow = side ? sRowT : sRowX;
      u32* dst = side ? valT : valX;
#pragma unroll
      for (int h = 0; h < 2; ++h) {
        int h0 = h * 32;
        for (int idx = tid; idx < 256 * 8; idx += 256) {
          int r = idx >> 3, f = idx & 7;
          int row = sRow[r];
          if (row >= 0) {
            float4 v = *(const float4*)(src + (size_t)row * DIMS + d0 + h0 + f * 4);
            pl[f * 4 + 0][r] = v.x;
            pl[f * 4 + 1][r] = v.y;
            pl[f * 4 + 2][r] = v.z;
            pl[f * 4 + 3][r] = v.w;
          }
        }
        __syncthreads();
        if (inr) {
          bool v2 = sRow[tid] >= 0;
          u32 pv = sPv[tid];
          for (int dl = 0; dl < 32; ++dl) {
            u32 e = v2 ? enc_f(pl[dl][tid]) : pv;
            dst[(size_t)(h0 + dl) * SEG_STRIDE + pos] = e;
          }
        }
        __syncthreads();
      }
    }
    return;
  }

  // ---- generic fallback (Dbc != 64)
  if (!inr) return;
  u32* dx = valX + pos;
  u32* dt = valT + pos;
  if (vld) {
    int w = smo[c] + rel;
    int iX = idxX[w], iT = idxT[w];
    const float* xr = x + (size_t)iX * DIMS + d0;
    const float* tr = tgt + (size_t)iT * DIMS + d0;
    for (int d = 0; d < Dbc; ++d) {
      dx[(size_t)d * SEG_STRIDE] = enc_f(xr[d]);
      dt[(size_t)d * SEG_STRIDE] = enc_f(tr[d]);
    }
  } else {
    u32 pv = (sp2[c] > CHUNK && ((rel >> 14) & 1)) ? 0u : 0xFFFFFFFFu;
    for (int d = 0; d < Dbc; ++d) {
      dx[(size_t)d * SEG_STRIDE] = pv;
      dt[(size_t)d * SEG_STRIDE] = pv;
    }
  }
}

// ---------------- K5: per-16K-chunk windowed bitonic sort (round-8 form).
// Write-out is limited to the valid prefix for small clusters: memory beyond v
// already holds the identical 0xFF pads written by k_gather (ascending sort
// leaves all pads at positions >= v), so those writes are elided.
__global__ __launch_bounds__(STH, 8) void k_sort(
    u32* __restrict__ vbase, const int* __restrict__ pG, const int* __restrict__ pOffG,
    const int* __restrict__ mG)
{
  __shared__ __align__(16) u32 lds[CHUNK];
  uint4* lds4 = (uint4*)lds;
  int t = blockIdx.x, c = -1, sub = 0, acc = 0;
  for (int cc = 0; cc < KCL; ++cc) {
    int pc0 = pG[cc];
    int nc = (pc0 > CHUNK) ? (pc0 / CHUNK) : 1;
    if (t < acc + nc) { c = cc; sub = t - acc; break; }
    acc += nc;
  }
  if (c < 0) return;
  int pc = pG[c];
  u32 CH = (u32)min(pc, CHUNK);
  u32 gb = (u32)sub * (u32)CHUNK;
  int v = mG[c] - (int)gb;                 // valid elements in this chunk
  if (v > (int)CH) v = (int)CH;
  if (v <= 0) return;                      // all-pad chunk
  u32 W = 32u;                             // sort window = next pow2 >= v
  while (W < (u32)v) W <<= 1;
  if (W > CH) W = CH;
  bool desc = (pc > CHUNK) && (sub & 1);
  u32 inv = desc ? 0xFFFFFFFFu : 0u;
  u32* seg = vbase + (size_t)blockIdx.y * SEG_STRIDE + pOffG[c] + gb;
  uint4* gp4 = (uint4*)seg;
  u32 tid = threadIdx.x;
  u32 lane = tid & 63u;
  u32 wv = tid >> 6;
  u32 ub = tid << 2;            // first unit of this thread's 16-elem tile
  u32 bas = tid << 4;           // first element index (window-local)
  bool act = (bas < W);
  u32 RU = wv << 8;             // wave run base, units
  u32 runBase = wv << 10;       // wave run base, elements
  bool wact = (runBase < W);
  u32 Lw = W - runBase; if (Lw > 1024u) Lw = 1024u;
  u32 r0,r1,r2,r3,r4,r5,r6,r7,r8,r9,r10,r11,r12,r13,r14,r15;

  // ---- Phase A: global -> regs, 16-sort, wave-local stages (no barriers)
  if (act) {
    uint4 a0 = gp4[ub + 0], a1 = gp4[ub + 1], a2 = gp4[ub + 2], a3 = gp4[ub + 3];
    r0 = a0.x^inv; r1 = a0.y^inv; r2  = a0.z^inv; r3  = a0.w^inv;
    r4 = a1.x^inv; r5 = a1.y^inv; r6  = a1.z^inv; r7  = a1.w^inv;
    r8 = a2.x^inv; r9 = a2.y^inv; r10 = a2.z^inv; r11 = a2.w^inv;
    r12 = a3.x^inv; r13 = a3.y^inv; r14 = a3.z^inv; r15 = a3.w^inv;
    bool D = ((bas & 16u) == 0u);
    SORT16F(D);
    STORETILE16(lds4);
  }
  if (wact) {
    for (u32 k = 32u; k <= Lw; k <<= 1) {
      wave_tail(lds4, RU, Lw, 0u, k, k >> 1, lane);
      if (act) {
        LOADTILE16(lds4);
        bool D = ((bas & k) == 0u);
        MERGE16F(D);
        STORETILE16(lds4);
      }
    }
  }

  // ---- Phase B: cross-wave stages (W >= 2048)
  if (W >= 2048u) {
    __syncthreads();
    for (u32 k = 2048u; k <= W; k <<= 1) {
      u32 jt = k >> 1;
      if (jt >= 8192u) {                  // k = 16384: strides 8192..1024
        cross3(lds4, W, 0u, k, 8192u, tid);
        __syncthreads();
        cross1(lds4, W, 0u, k, 1024u, tid);
        __syncthreads();
      } else if (jt == 4096u) {
        cross3(lds4, W, 0u, k, 4096u, tid);
        __syncthreads();
      } else if (jt == 2048u) {
        cross2(lds4, W, 0u, k, 2048u, tid);
        __syncthreads();
      } else {
        cross1(lds4, W, 0u, k, 1024u, tid);
        __syncthreads();
      }
      if (wact) {
        wave_tail(lds4, RU, Lw, 0u, k, 512u, lane);
        if (act) {
          LOADTILE16(lds4);
          bool D = ((bas & k) == 0u);
          MERGE16F(D);
          STORETILE16(lds4);
        }
      }
      if (k < W) __syncthreads();
    }
  }

  // ---- lane-striped dense write-out.
  // Small clusters: only ceil(v/4) uint4s — the tail [v, W) is ascending-sorted
  // 0xFF pads, bit-identical to what k_gather already wrote there.
  // Big clusters: full W (gpass/gfinish consume every element incl. pads).
  __syncthreads();
  u32 ulim = (pc > CHUNK) ? (W >> 2) : (((u32)v + 3u) >> 2);
  for (u32 uu = tid; uu < ulim; uu += STH) {
    uint4 q = lds4[U4(uu)];
    q.x ^= inv; q.y ^= inv; q.z ^= inv; q.w ^= inv;
    gp4[uu] = q;
  }
}

// ---------------- K6: global bitonic pass for big segments (j >= CHUNK).
__global__ __launch_bounds__(256) void k_gpass(
    u32* __restrict__ vbase, const int* __restrict__ pG, const int* __restrict__ pOffG,
    int kk, int j)
{
  u32* base = vbase + (size_t)blockIdx.y * SEG_STRIDE;
  int pb[KCL]; int tot = 0;
#pragma unroll
  for (int c = 0; c < KCL; ++c) {
    pb[c] = tot;
    int pc = pG[c];
    if (pc >= kk) tot += pc >> 1;
  }
  for (int g4 = (blockIdx.x * 256 + threadIdx.x) << 2; g4 < tot; g4 += gridDim.x * 256 * 4) {
    int c = 0;
#pragma unroll
    for (int cc = 1; cc < KCL; ++cc) c += (g4 >= pb[cc]) ? 1 : 0;
    int u = g4 - pb[c];
    int i = ((u & ~(j - 1)) << 1) | (u & (j - 1));
    bool up = ((i & kk) == 0);
    u32* s2 = base + pOffG[c];
    uint4 A = *(const uint4*)(s2 + i);
    uint4 B = *(const uint4*)(s2 + i + j);
    CS(A.x, B.x, up) CS(A.y, B.y, up) CS(A.z, B.z, up) CS(A.w, B.w, up)
    *(uint4*)(s2 + i) = A;
    *(uint4*)(s2 + i + j) = B;
  }
}

// ---------------- K7: finish big-segment stage (strides <= 8192) in 64KB LDS.
__global__ __launch_bounds__(STH) void k_gfinish(
    u32* __restrict__ vbase, const int* __restrict__ pG, const int* __restrict__ pOffG, int kk)
{
  __shared__ __align__(16) u32 lds[CHUNK];
  uint4* lds4 = (uint4*)lds;
  int t = blockIdx.x, c = -1, sub = 0, acc = 0;
  for (int cc = 0; cc < KCL; ++cc) {
    int pc = pG[cc];
    if (pc < kk) continue;
    int nc = pc / CHUNK;
    if (t < acc + nc) { c = cc; sub = t - acc; break; }
    acc += nc;
  }
  if (c < 0) return;
  u32 gb = (u32)sub * (u32)CHUNK;
  u32* seg = vbase + (size_t)blockIdx.y * SEG_STRIDE + pOffG[c] + gb;
  uint4* gp4 = (uint4*)seg;
  u32 tid = threadIdx.x;
  u32 lane = tid & 63u;
  u32 wv = tid >> 6;
  u32 RU = wv << 8;
  u32 ub = tid << 2;
  u32 bas = tid << 4;
  u32 r0,r1,r2,r3,r4,r5,r6,r7,r8,r9,r10,r11,r12,r13,r14,r15;

  for (u32 uu = tid; uu < CHUNK / 4; uu += STH) lds4[U4(uu)] = gp4[uu];
  __syncthreads();
  cross3(lds4, (u32)CHUNK, gb, (u32)kk, 8192u, tid);   // strides 8192..2048
  __syncthreads();
  cross1(lds4, (u32)CHUNK, gb, (u32)kk, 1024u, tid);   // stride 1024
  __syncthreads();
  wave_tail(lds4, RU, 1024u, gb, (u32)kk, 512u, lane); // strides 512..16
  {
    LOADTILE16(lds4);
    bool up = (((gb + bas) & (u32)kk) == 0u);
    MERGE16F(up);
    STORETILE16(lds4);
  }
  __syncthreads();
  for (u32 uu = tid; uu < CHUNK / 4; uu += STH) gp4[uu] = lds4[U4(uu)];
}

// ---------------- K8: windowed |diff| reduce over valid positions only.
__global__ __launch_bounds__(256) void k_reduce(
    const u32* __restrict__ valX, const u32* __restrict__ valT,
    const int* __restrict__ pOffG, const int* __restrict__ mOffG,
    const int* __restrict__ nloG,
    const float* __restrict__ wG, float* __restrict__ lossAcc)
{
  __shared__ int spOff[KCL];
  __shared__ int smo[KCL + 1];
  __shared__ int snlo[KCL];
  __shared__ float swt[KCL];
  __shared__ float red[256];
  int tid = threadIdx.x;
  if (tid <= KCL) smo[tid] = mOffG[tid];
  if (tid < KCL) { spOff[tid] = pOffG[tid]; snlo[tid] = nloG[tid]; swt[tid] = wG[tid]; }
  __syncthreads();
  int d = blockIdx.y;
  const u32* vx = valX + (size_t)d * SEG_STRIDE;
  const u32* vt = valT + (size_t)d * SEG_STRIDE;
  int M = smo[KCL];
  float s = 0.f;
  for (int w = blockIdx.x * 256 + tid; w < M; w += gridDim.x * 256) {
    int c = 0;
#pragma unroll
    for (int cc = 1; cc < KCL; ++cc) c += (w >= smo[cc]) ? 1 : 0;
    int pos = spOff[c] + snlo[c] + (w - smo[c]);
    float a = dec_f(vx[pos]), b = dec_f(vt[pos]);
    s += fabsf(a - b) * swt[c];
  }
  red[tid] = s;
  __syncthreads();
  for (int st = 128; st > 0; st >>= 1) {
    if (tid < st) red[tid] += red[tid + st];
    __syncthreads();
  }
  if (tid == 0) atomicAdd(lossAcc, red[0]);
}

// ---------------- K9: final scalar
__global__ void k_final(const float* __restrict__ lossAcc, const float* __restrict__ loss_fil,
                        float* __restrict__ out)
{
  out[0] = *lossAcc + *loss_fil;
}

extern "C" void kernel_launch(void* const* d_in, const int* in_sizes, int n_in,
                              void* d_out, int out_size, void* d_ws, size_t ws_size,
                              hipStream_t stream)
{
  const float* x       = (const float*)d_in[0];
  const float* centers = (const float*)d_in[1];
  const float* ftarget = (const float*)d_in[2];
  const float* tgt     = (const float*)d_in[3];
  const int*   predT   = (const int*)d_in[4];
  float* out = (float*)d_out;

  char* ws = (char*)d_ws;
  float* fill_sum = (float*)(ws + 0);       // 16 f (zeroed)
  float* lossAcc  = (float*)(ws + 64);      // zeroed
  float* loss_fil = (float*)(ws + 68);      // zeroed
  int*   m_buf    = (int*)(ws + 128);
  float* w_buf    = (float*)(ws + 192);
  int*   p_buf    = (int*)(ws + 256);
  int*   pOff     = (int*)(ws + 320);       // 17 ints
  int*   mOff     = (int*)(ws + 400);       // 17 ints
  u32* histX = (u32*)(ws + 512);            // 512*16*4 = 32768
  u32* histT = (u32*)(ws + 512 + 32768);
  u32* baseX = (u32*)(ws + 512 + 65536);
  u32* baseT = (u32*)(ws + 512 + 98304);
  int* predX = (int*)(ws + 131584);         // 524288
  int* idxX  = (int*)(ws + 655872);         // 524288 (compact, Sum(m) <= 131072)
  int* idxT  = (int*)(ws + 1180160);        // 524288
  int* nlo_buf = (int*)(ws + 1704448);      // 16 ints
  u32* vbase = (u32*)(ws + VOFF);

  size_t avail_elems = (ws_size > VOFF) ? ((ws_size - VOFF) / 4) : 0;
  int Db = (int)(avail_elems / (2ull * SEG_STRIDE));
  if (Db > DIMS) Db = DIMS;
  if (Db >= 4) Db &= ~3;
  if (Db < 1) Db = 1;

  hipMemsetAsync(ws, 0, 128, stream);
  k_assign<<<NBLK, 256, 0, stream>>>(x, centers, predT, predX, fill_sum, histX, histT);
  k_scan<<<1, 512, 0, stream>>>(histX, histT, baseX, baseT, fill_sum, ftarget,
                                m_buf, w_buf, p_buf, pOff, mOff, nlo_buf, loss_fil);
  k_rank<<<NBLK, 256, 0, stream>>>(predX, predT, baseX, baseT, m_buf, mOff, idxX, idxT);

  for (int d0 = 0; d0 < DIMS; d0 += Db) {
    int Dbc = (Db < DIMS - d0) ? Db : (DIMS - d0);
    u32* valX = vbase;
    u32* valT = vbase + (size_t)Dbc * SEG_STRIDE;
    // 1028 * 256 = 263168 >= worst-case Sum(p); values + pads in one pass
    k_gather<<<1028, 256, 0, stream>>>(x, tgt, idxX, idxT, pOff, mOff, m_buf, p_buf,
                                       valX, valT, d0, Dbc);
    // worst-case chunk count: Sum max(1, p/16384) <= 26 -> 28 x-blocks (extras exit)
    k_sort<<<dim3(28, 2 * Dbc), STH, 0, stream>>>(vbase, p_buf, pOff, m_buf);
    // parallel merge stages for clusters with p > 16384 (early-exit when none)
    for (int kk = 2 * CHUNK; kk <= N_ROWS; kk <<= 1) {
      int gx = (kk == 2 * CHUNK) ? 32 : 8;
      for (int j = kk >> 1; j >= CHUNK; j >>= 1)
        k_gpass<<<dim3(gx, 2 * Dbc), 256, 0, stream>>>(vbase, p_buf, pOff, kk, j);
      // chunks with p >= kk bounded by Sum(p)/CHUNK <= 16 -> 18 x-blocks
      k_gfinish<<<dim3(18, 2 * Dbc), STH, 0, stream>>>(vbase, p_buf, pOff, kk);
    }
    k_reduce<<<dim3(32, Dbc), 256, 0, stream>>>(valX, valT, pOff, mOff, nlo_buf,
                                                w_buf, lossAcc);
  }
  k_final<<<1, 1, 0, stream>>>(lossAcc, loss_fil, out);
}

// Round 14
// 596.857 us; speedup vs baseline: 1.0415x; 1.0121x over previous
//
#include <hip/hip_runtime.h>
#include <stdint.h>

#define N_ROWS 131072
#define DIMS 64
#define KCL 16
#define BETA 4.0f
#define NBLK 512            // N_ROWS / 256
#define CHUNK 16384         // elements per LDS sort chunk (16384 * 4B = 64KB LDS)
#define STH 1024            // sort threads per block (16 waves)
#define SEG_STRIDE 263168   // u32 elements per (dim,side)
#define VOFF (1u<<21)

typedef unsigned long long u64;
typedef unsigned int u32;

__device__ __forceinline__ u32 enc_f(float f) {
  u32 u = __float_as_uint(f);
  return (u & 0x80000000u) ? ~u : (u | 0x80000000u);
}
__device__ __forceinline__ float dec_f(u32 e) {
  u32 u = (e & 0x80000000u) ? (e & 0x7FFFFFFFu) : ~e;
  return __uint_as_float(u);
}
// unit (uint4) granularity bank swizzle
__device__ __forceinline__ u32 U4(u32 u) { return u ^ ((u >> 3) & 7u); }

#define CS(a,b,dd) { u32 _mn = min(a,b), _mx = max(a,b); a = (dd)?_mn:_mx; b = (dd)?_mx:_mn; }
#define CSV(A,B,D) { CS(A.x,B.x,D) CS(A.y,B.y,D) CS(A.z,B.z,D) CS(A.w,B.w,D) }

// bitonic merge of 16 named regs, direction D (strides 8,4,2,1)
#define M16G(a,b,c,d,e,f,g,h,i2,j2,k2,l,m,n,o,p,D) \
  CS(a,i2,D) CS(b,j2,D) CS(c,k2,D) CS(d,l,D) CS(e,m,D) CS(f,n,D) CS(g,o,D) CS(h,p,D) \
  CS(a,e,D)  CS(b,f,D)  CS(c,g,D)  CS(d,h,D) CS(i2,m,D) CS(j2,n,D) CS(k2,o,D) CS(l,p,D) \
  CS(a,c,D)  CS(b,d,D)  CS(e,g,D)  CS(f,h,D) CS(i2,k2,D) CS(j2,l,D) CS(m,o,D) CS(n,p,D) \
  CS(a,b,D)  CS(c,d,D)  CS(e,f,D)  CS(g,h,D) CS(i2,j2,D) CS(k2,l,D) CS(m,n,D) CS(o,p,D)

// full bitonic sort of 16 named regs with final direction D
#define SORT16G(a,b,c,d,e,f,g,h,i2,j2,k2,l,m,n,o,p,D) \
  CS(a,b,D) CS(c,d,!(D)) CS(e,f,D) CS(g,h,!(D)) CS(i2,j2,D) CS(k2,l,!(D)) CS(m,n,D) CS(o,p,!(D)) \
  CS(a,c,D) CS(b,d,D) CS(e,g,!(D)) CS(f,h,!(D)) CS(i2,k2,D) CS(j2,l,D) CS(m,o,!(D)) CS(n,p,!(D)) \
  CS(a,b,D) CS(c,d,D) CS(e,f,!(D)) CS(g,h,!(D)) CS(i2,j2,D) CS(k2,l,D) CS(m,n,!(D)) CS(o,p,!(D)) \
  CS(a,e,D) CS(b,f,D) CS(c,g,D) CS(d,h,D) CS(i2,m,!(D)) CS(j2,n,!(D)) CS(k2,o,!(D)) CS(l,p,!(D)) \
  CS(a,c,D) CS(b,d,D) CS(e,g,D) CS(f,h,D) CS(i2,k2,!(D)) CS(j2,l,!(D)) CS(m,o,!(D)) CS(n,p,!(D)) \
  CS(a,b,D) CS(c,d,D) CS(e,f,D) CS(g,h,D) CS(i2,j2,!(D)) CS(k2,l,!(D)) CS(m,n,!(D)) CS(o,p,!(D)) \
  M16G(a,b,c,d,e,f,g,h,i2,j2,k2,l,m,n,o,p,D)

#define MERGE16F(D) M16G(r0,r1,r2,r3,r4,r5,r6,r7,r8,r9,r10,r11,r12,r13,r14,r15,D)
#define SORT16F(D)  SORT16G(r0,r1,r2,r3,r4,r5,r6,r7,r8,r9,r10,r11,r12,r13,r14,r15,D)

#define LOADTILE16(src) \
  { uint4 _a0=src[U4(ub+0)],_a1=src[U4(ub+1)],_a2=src[U4(ub+2)],_a3=src[U4(ub+3)]; \
    r0=_a0.x;r1=_a0.y;r2=_a0.z;r3=_a0.w; r4=_a1.x;r5=_a1.y;r6=_a1.z;r7=_a1.w; \
    r8=_a2.x;r9=_a2.y;r10=_a2.z;r11=_a2.w; r12=_a3.x;r13=_a3.y;r14=_a3.z;r15=_a3.w; }

#define STORETILE16(dst) \
  { dst[U4(ub+0)]=make_uint4(r0,r1,r2,r3);   dst[U4(ub+1)]=make_uint4(r4,r5,r6,r7); \
    dst[U4(ub+2)]=make_uint4(r8,r9,r10,r11); dst[U4(ub+3)]=make_uint4(r12,r13,r14,r15); }

// ---- WAVE-LOCAL bitonic rounds: strides jtop..16 within this wave's 1024-run.
// DS ops of one wave execute in program order on CDNA -> no barriers needed.
// 2-fused trips {j, j/2} with ALL 64 lanes active (16-elem instances).
__device__ __forceinline__ void wave_tail(uint4* lds4, u32 RU, u32 Lw, u32 gbase,
                                          u32 k, u32 jtop, u32 lane)
{
  u32 j = jtop;
  while (j >= 32u) {
    u32 ud = j >> 3;                      // units between the 4 loads (= j/2 elems)
    if (lane < (Lw >> 4)) {               // 16-elem instances
      u32 bu = RU + (((lane & ~(ud - 1u)) << 2) | (lane & (ud - 1u)));
      bool up = (((gbase + (bu << 2)) & k) == 0u);
      uint4 A0 = lds4[U4(bu)],           A1 = lds4[U4(bu + ud)],
            A2 = lds4[U4(bu + 2u * ud)], A3 = lds4[U4(bu + 3u * ud)];
      CSV(A0,A2,up) CSV(A1,A3,up)         // stride j
      CSV(A0,A1,up) CSV(A2,A3,up)         // stride j/2
      lds4[U4(bu)] = A0;           lds4[U4(bu + ud)] = A1;
      lds4[U4(bu + 2u * ud)] = A2; lds4[U4(bu + 3u * ud)] = A3;
    }
    j >>= 2;
  }
  if (j == 16u) {                         // single stride-16 round
    u32 total = Lw >> 3;                  // 8-elem instances
    for (u32 inst = lane; inst < total; inst += 64u) {
      u32 bu = RU + (((inst & ~3u) << 1) | (inst & 3u));
      bool up = (((gbase + (bu << 2)) & k) == 0u);
      uint4 A = lds4[U4(bu)], B = lds4[U4(bu + 4u)];
      CSV(A,B,up)
      lds4[U4(bu)] = A; lds4[U4(bu + 4u)] = B;
    }
  }
}

// ---- BLOCK-WIDE fused cross-wave trips.
__device__ __forceinline__ void cross1(uint4* lds4, u32 Wn, u32 gb, u32 k, u32 jtop, u32 tid)
{
  u32 ud = jtop >> 2;
  u32 total = Wn >> 3;
  for (u32 inst = tid; inst < total; inst += STH) {
    u32 bu = ((inst & ~(ud - 1u)) << 1) | (inst & (ud - 1u));
    bool up = (((gb + (bu << 2)) & k) == 0u);
    uint4 A = lds4[U4(bu)], B = lds4[U4(bu + ud)];
    CSV(A,B,up)
    lds4[U4(bu)] = A; lds4[U4(bu + ud)] = B;
  }
}
__device__ __forceinline__ void cross2(uint4* lds4, u32 Wn, u32 gb, u32 k, u32 jtop, u32 tid)
{
  u32 ud = jtop >> 3;
  u32 total = Wn >> 4;
  for (u32 inst = tid; inst < total; inst += STH) {
    u32 bu = ((inst & ~(ud - 1u)) << 2) | (inst & (ud - 1u));
    bool up = (((gb + (bu << 2)) & k) == 0u);
    uint4 A0 = lds4[U4(bu)],            A1 = lds4[U4(bu + ud)],
          A2 = lds4[U4(bu + 2u * ud)],  A3 = lds4[U4(bu + 3u * ud)];
    CSV(A0,A2,up) CSV(A1,A3,up)
    CSV(A0,A1,up) CSV(A2,A3,up)
    lds4[U4(bu)] = A0;           lds4[U4(bu + ud)] = A1;
    lds4[U4(bu + 2u * ud)] = A2; lds4[U4(bu + 3u * ud)] = A3;
  }
}
__device__ __forceinline__ void cross3(uint4* lds4, u32 Wn, u32 gb, u32 k, u32 jtop, u32 tid)
{
  u32 ud = jtop >> 4;
  u32 total = Wn >> 5;
  for (u32 inst = tid; inst < total; inst += STH) {
    u32 bu = ((inst & ~(ud - 1u)) << 3) | (inst & (ud - 1u));
    bool up = (((gb + (bu << 2)) & k) == 0u);
    uint4 A0 = lds4[U4(bu)],            A1 = lds4[U4(bu + ud)],
          A2 = lds4[U4(bu + 2u * ud)],  A3 = lds4[U4(bu + 3u * ud)],
          A4 = lds4[U4(bu + 4u * ud)],  A5 = lds4[U4(bu + 5u * ud)],
          A6 = lds4[U4(bu + 6u * ud)],  A7 = lds4[U4(bu + 7u * ud)];
    CSV(A0,A4,up) CSV(A1,A5,up) CSV(A2,A6,up) CSV(A3,A7,up)
    CSV(A0,A2,up) CSV(A1,A3,up) CSV(A4,A6,up) CSV(A5,A7,up)
    CSV(A0,A1,up) CSV(A2,A3,up) CSV(A4,A5,up) CSV(A6,A7,up)
    lds4[U4(bu)] = A0;           lds4[U4(bu + ud)] = A1;
    lds4[U4(bu + 2u * ud)] = A2; lds4[U4(bu + 3u * ud)] = A3;
    lds4[U4(bu + 4u * ud)] = A4; lds4[U4(bu + 5u * ud)] = A5;
    lds4[U4(bu + 6u * ud)] = A6; lds4[U4(bu + 7u * ud)] = A7;
  }
}

// ---------------- K1: cluster assign + softmax filling + per-block histograms
__global__ __launch_bounds__(256) void k_assign(
    const float* __restrict__ x, const float* __restrict__ centers,
    const int* __restrict__ predT, int* __restrict__ predX,
    float* __restrict__ fill_sum, u32* __restrict__ histX, u32* __restrict__ histT)
{
  __shared__ float c[KCL][DIMS];
  __shared__ float cn[KCL];
  __shared__ float fs[KCL];
  __shared__ u32 hx[KCL], ht[KCL];
  int tid = threadIdx.x;
  for (int t = tid; t < KCL * DIMS; t += 256) c[t / DIMS][t % DIMS] = centers[t];
  if (tid < KCL) { fs[tid] = 0.f; hx[tid] = 0; ht[tid] = 0; }
  __syncthreads();
  if (tid < KCL) {
    float s = 0.f;
    for (int d = 0; d < DIMS; ++d) s += c[tid][d] * c[tid][d];
    cn[tid] = s;
  }
  __syncthreads();
  int i = blockIdx.x * 256 + tid;
  const float4* xr = (const float4*)(x + (size_t)i * DIMS);
  float dot[KCL];
#pragma unroll
  for (int k = 0; k < KCL; ++k) dot[k] = 0.f;
  for (int t = 0; t < DIMS / 4; ++t) {
    float4 v = xr[t];
#pragma unroll
    for (int k = 0; k < KCL; ++k)
      dot[k] += v.x * c[k][4 * t] + v.y * c[k][4 * t + 1] + v.z * c[k][4 * t + 2] + v.w * c[k][4 * t + 3];
  }
  float sc[KCL];
  float smin = 3.0e38f; int kmin = 0;
#pragma unroll
  for (int k = 0; k < KCL; ++k) {
    sc[k] = cn[k] - 2.f * dot[k];
    if (sc[k] < smin) { smin = sc[k]; kmin = k; }
  }
  float e[KCL]; float esum = 0.f;
#pragma unroll
  for (int k = 0; k < KCL; ++k) { e[k] = expf(-BETA * (sc[k] - smin)); esum += e[k]; }
  float inv = 1.f / esum;
#pragma unroll
  for (int k = 0; k < KCL; ++k) atomicAdd(&fs[k], e[k] * inv);
  predX[i] = kmin;
  atomicAdd(&hx[kmin], 1u);
  atomicAdd(&ht[predT[i]], 1u);
  __syncthreads();
  if (tid < KCL) {
    histX[blockIdx.x * KCL + tid] = hx[tid];
    histT[blockIdx.x * KCL + tid] = ht[tid];
    atomicAdd(&fill_sum[tid], fs[tid]);
  }
}

// ---------------- K2: scan hists -> bases, totals, m, w, p, pOff, mOff, nlo, loss_fil
__global__ __launch_bounds__(512) void k_scan(
    const u32* __restrict__ histX, const u32* __restrict__ histT,
    u32* __restrict__ baseX, u32* __restrict__ baseT,
    const float* __restrict__ fill_sum, const float* __restrict__ ftarget,
    int* __restrict__ m_out, float* __restrict__ w_out,
    int* __restrict__ p_out, int* __restrict__ pOff_out, int* __restrict__ mOff_out,
    int* __restrict__ nlo_out, float* __restrict__ loss_fil)
{
  __shared__ u32 part[2][KCL][17];
  __shared__ u32 tot[2][KCL];
  __shared__ float sq[KCL];
  __shared__ int sp[KCL];
  __shared__ int smv[KCL];
  int tid = threadIdx.x;
  int side = tid >> 8;
  int rem = tid & 255;
  int c = rem >> 4;
  int sub = rem & 15;
  const u32* hist = side ? histT : histX;
  u32* base = side ? baseT : baseX;
  int b0 = sub * 32;
  u32 s = 0;
  for (int b = b0; b < b0 + 32; ++b) s += hist[b * KCL + c];
  part[side][c][sub] = s;
  __syncthreads();
  if (sub == 0) {
    u32 run = 0;
    for (int t = 0; t < 16; ++t) { u32 v = part[side][c][t]; part[side][c][t] = run; run += v; }
    tot[side][c] = run;
  }
  __syncthreads();
  u32 run = part[side][c][sub];
  for (int b = b0; b < b0 + 32; ++b) { base[b * KCL + c] = run; run += hist[b * KCL + c]; }
  if (tid < KCL) {
    int m = min((int)tot[0][tid], (int)tot[1][tid]);
    m_out[tid] = m;
    smv[tid] = m;
    w_out[tid] = (m > 0) ? 1.f / ((float)m * (float)DIMS) : 0.f;
    int pp = 32;
    while (pp < m) pp <<= 1;
    sp[tid] = pp;
    p_out[tid] = pp;
    // nlo = pads residing in descending (odd) 16K chunks -> land at segment FRONT
    // after the full ascending merge; valid window is [nlo, nlo+m).
    int nlo = 0;
    if (pp > CHUNK) {
      int nch = pp / CHUNK;
      for (int j = 1; j < nch; j += 2) {
        int v = m - j * CHUNK;
        if (v < 0) v = 0;
        if (v > CHUNK) v = CHUNK;
        nlo += CHUNK - v;
      }
    }
    nlo_out[tid] = nlo;
    float d = fill_sum[tid] / (float)N_ROWS - ftarget[tid];
    sq[tid] = d * d;
  }
  __syncthreads();
  if (tid == 0) {
    float s2 = 0.f;
    int acc = 0, macc = 0;
    for (int k = 0; k < KCL; ++k) {
      s2 += sq[k];
      pOff_out[k] = acc;
      acc += sp[k];
      mOff_out[k] = macc;
      macc += smv[k];
    }
    pOff_out[KCL] = acc;
    mOff_out[KCL] = macc;
    *loss_fil = s2 / (float)KCL;
  }
}

// ---------------- K3: ordered within-cluster rank -> compact inverse index
__global__ __launch_bounds__(256) void k_rank(
    const int* __restrict__ predX, const int* __restrict__ predT,
    const u32* __restrict__ baseX, const u32* __restrict__ baseT,
    const int* __restrict__ mG, const int* __restrict__ mOffG,
    int* __restrict__ idxX, int* __restrict__ idxT)
{
  __shared__ int wcX[4][KCL], wcT[4][KCL];
  __shared__ int smo[KCL], sm2[KCL];
  int tid = threadIdx.x;
  int lane = tid & 63, wave = tid >> 6;
  if (tid < KCL) { smo[tid] = mOffG[tid]; sm2[tid] = mG[tid]; }
  int i = blockIdx.x * 256 + tid;
  int kx = predX[i], kt = predT[i];
  u64 below = (1ull << lane) - 1ull;
  int lrX = 0, lrT = 0;
  for (int cc = 0; cc < KCL; ++cc) {
    u64 mx = __ballot(kx == cc);
    u64 mt = __ballot(kt == cc);
    if (kx == cc) lrX = __popcll(mx & below);
    if (kt == cc) lrT = __popcll(mt & below);
    if (lane == 0) { wcX[wave][cc] = __popcll(mx); wcT[wave][cc] = __popcll(mt); }
  }
  __syncthreads();
  int wbX = 0, wbT = 0;
  for (int w2 = 0; w2 < wave; ++w2) { wbX += wcX[w2][kx]; wbT += wcT[w2][kt]; }
  int rX = (int)baseX[blockIdx.x * KCL + kx] + wbX + lrX;
  int rT = (int)baseT[blockIdx.x * KCL + kt] + wbT + lrT;
  if (rX < sm2[kx]) idxX[smo[kx] + rX] = i;
  if (rT < sm2[kt]) idxT[smo[kt] + rT] = i;
}

// ---------------- K4: gather rows into cluster-partitioned dim planes + pads.
// Coalesced row loads transposed through LDS (round-8 verified form).
// Pad stores are SKIPPED for small clusters (p <= CHUNK): k_sort materializes
// those pads in registers. Big clusters still get pads in memory (gpass /
// gfinish / all-pad chunks consume them).
__global__ __launch_bounds__(256) void k_gather(
    const float* __restrict__ x, const float* __restrict__ tgt,
    const int* __restrict__ idxX, const int* __restrict__ idxT,
    const int* __restrict__ pOffG, const int* __restrict__ mOffG,
    const int* __restrict__ mG, const int* __restrict__ pG,
    u32* __restrict__ valX, u32* __restrict__ valT, int d0, int Dbc)
{
  __shared__ int spOff[KCL + 1];
  __shared__ int smo[KCL], sm2[KCL], sp2[KCL];
  __shared__ float pl[32][257];       // planes[d_local][pos_local], padded
  __shared__ int sRowX[256], sRowT[256];
  __shared__ u32 sPv[256];
  int tid = threadIdx.x;
  if (tid <= KCL) spOff[tid] = pOffG[tid];
  if (tid < KCL) { smo[tid] = mOffG[tid]; sm2[tid] = mG[tid]; sp2[tid] = pG[tid]; }
  __syncthreads();
  int pos = blockIdx.x * 256 + tid;
  bool inr = pos < spOff[KCL];
  int c = 0, rel = 0;
  bool vld = false;
  if (inr) {
#pragma unroll
    for (int cc = 1; cc < KCL; ++cc) c += (pos >= spOff[cc]) ? 1 : 0;
    rel = pos - spOff[c];
    vld = rel < sm2[c];
  }

  if (Dbc == 64) {
    int w = vld ? (smo[c] + rel) : 0;
    sRowX[tid] = vld ? idxX[w] : -1;
    sRowT[tid] = vld ? idxT[w] : -1;
    sPv[tid] = inr ? ((sp2[c] > CHUNK && ((rel >> 14) & 1)) ? 0u : 0xFFFFFFFFu) : 0u;
    __syncthreads();
    bool wrPad = inr && !vld && (sp2[c] > CHUNK);   // pads only for big clusters
#pragma unroll
    for (int side = 0; side < 2; ++side) {
      const float* src = side ? tgt : x;
      const int* sRow = side ? sRowT : sRowX;
      u32* dst = side ? valT : valX;
#pragma unroll
      for (int h = 0; h < 2; ++h) {
        int h0 = h * 32;
        for (int idx = tid; idx < 256 * 8; idx += 256) {
          int r = idx >> 3, f = idx & 7;
          int row = sRow[r];
          if (row >= 0) {
            float4 v = *(const float4*)(src + (size_t)row * DIMS + d0 + h0 + f * 4);
            pl[f * 4 + 0][r] = v.x;
            pl[f * 4 + 1][r] = v.y;
            pl[f * 4 + 2][r] = v.z;
            pl[f * 4 + 3][r] = v.w;
          }
        }
        __syncthreads();
        if (inr) {
          bool v2 = sRow[tid] >= 0;
          u32 pv = sPv[tid];
          if (v2) {
            for (int dl = 0; dl < 32; ++dl)
              dst[(size_t)(h0 + dl) * SEG_STRIDE + pos] = enc_f(pl[dl][tid]);
          } else if (wrPad) {
            for (int dl = 0; dl < 32; ++dl)
              dst[(size_t)(h0 + dl) * SEG_STRIDE + pos] = pv;
          }
        }
        __syncthreads();
      }
    }
    return;
  }

  // ---- generic fallback (Dbc != 64)
  if (!inr) return;
  u32* dx = valX + pos;
  u32* dt = valT + pos;
  if (vld) {
    int w = smo[c] + rel;
    int iX = idxX[w], iT = idxT[w];
    const float* xr = x + (size_t)iX * DIMS + d0;
    const float* tr = tgt + (size_t)iT * DIMS + d0;
    for (int d = 0; d < Dbc; ++d) {
      dx[(size_t)d * SEG_STRIDE] = enc_f(xr[d]);
      dt[(size_t)d * SEG_STRIDE] = enc_f(tr[d]);
    }
  } else if (sp2[c] > CHUNK) {
    u32 pv = ((rel >> 14) & 1) ? 0u : 0xFFFFFFFFu;
    for (int d = 0; d < Dbc; ++d) {
      dx[(size_t)d * SEG_STRIDE] = pv;
      dt[(size_t)d * SEG_STRIDE] = pv;
    }
  }
}

// ---------------- K5: per-16K-chunk windowed bitonic sort (round-8 form).
// Small clusters: pads [v, W) are materialized in REGISTERS (tiles fully
// beyond v skip the global load; the straddle tile loads and patches) — the
// memory tail holds garbage that nothing reads. Write-out limited to
// ceil(v/4) uint4s for small clusters. Big clusters unchanged (pads from
// memory, full-W write-out).
__global__ __launch_bounds__(STH, 8) void k_sort(
    u32* __restrict__ vbase, const int* __restrict__ pG, const int* __restrict__ pOffG,
    const int* __restrict__ mG)
{
  __shared__ __align__(16) u32 lds[CHUNK];
  uint4* lds4 = (uint4*)lds;
  int t = blockIdx.x, c = -1, sub = 0, acc = 0;
  for (int cc = 0; cc < KCL; ++cc) {
    int pc0 = pG[cc];
    int nc = (pc0 > CHUNK) ? (pc0 / CHUNK) : 1;
    if (t < acc + nc) { c = cc; sub = t - acc; break; }
    acc += nc;
  }
  if (c < 0) return;
  int pc = pG[c];
  u32 CH = (u32)min(pc, CHUNK);
  u32 gb = (u32)sub * (u32)CHUNK;
  int v = mG[c] - (int)gb;                 // valid elements in this chunk
  if (v > (int)CH) v = (int)CH;
  if (v <= 0) return;                      // all-pad chunk
  u32 W = 32u;                             // sort window = next pow2 >= v
  while (W < (u32)v) W <<= 1;
  if (W > CH) W = CH;
  bool desc = (pc > CHUNK) && (sub & 1);
  u32 inv = desc ? 0xFFFFFFFFu : 0u;
  u32* seg = vbase + (size_t)blockIdx.y * SEG_STRIDE + pOffG[c] + gb;
  uint4* gp4 = (uint4*)seg;
  u32 tid = threadIdx.x;
  u32 lane = tid & 63u;
  u32 wv = tid >> 6;
  u32 ub = tid << 2;            // first unit of this thread's 16-elem tile
  u32 bas = tid << 4;           // first element index (window-local)
  bool act = (bas < W);
  u32 RU = wv << 8;             // wave run base, units
  u32 runBase = wv << 10;       // wave run base, elements
  bool wact = (runBase < W);
  u32 Lw = W - runBase; if (Lw > 1024u) Lw = 1024u;
  u32 r0,r1,r2,r3,r4,r5,r6,r7,r8,r9,r10,r11,r12,r13,r14,r15;

  // ---- Phase A: global -> regs (register pads for small clusters), 16-sort,
  // wave-local stages (no barriers)
  if (act) {
    bool smallc = (pc <= CHUNK);
    u32 vv = (u32)v;
    if (!smallc || bas < vv) {
      uint4 a0 = gp4[ub + 0], a1 = gp4[ub + 1], a2 = gp4[ub + 2], a3 = gp4[ub + 3];
      r0 = a0.x^inv; r1 = a0.y^inv; r2  = a0.z^inv; r3  = a0.w^inv;
      r4 = a1.x^inv; r5 = a1.y^inv; r6  = a1.z^inv; r7  = a1.w^inv;
      r8 = a2.x^inv; r9 = a2.y^inv; r10 = a2.z^inv; r11 = a2.w^inv;
      r12 = a3.x^inv; r13 = a3.y^inv; r14 = a3.z^inv; r15 = a3.w^inv;
      if (smallc && bas + 16u > vv) {      // straddle tile: patch register pads
        if (bas + 0u  >= vv) r0  = 0xFFFFFFFFu;
        if (bas + 1u  >= vv) r1  = 0xFFFFFFFFu;
        if (bas + 2u  >= vv) r2  = 0xFFFFFFFFu;
        if (bas + 3u  >= vv) r3  = 0xFFFFFFFFu;
        if (bas + 4u  >= vv) r4  = 0xFFFFFFFFu;
        if (bas + 5u  >= vv) r5  = 0xFFFFFFFFu;
        if (bas + 6u  >= vv) r6  = 0xFFFFFFFFu;
        if (bas + 7u  >= vv) r7  = 0xFFFFFFFFu;
        if (bas + 8u  >= vv) r8  = 0xFFFFFFFFu;
        if (bas + 9u  >= vv) r9  = 0xFFFFFFFFu;
        if (bas + 10u >= vv) r10 = 0xFFFFFFFFu;
        if (bas + 11u >= vv) r11 = 0xFFFFFFFFu;
        if (bas + 12u >= vv) r12 = 0xFFFFFFFFu;
        if (bas + 13u >= vv) r13 = 0xFFFFFFFFu;
        if (bas + 14u >= vv) r14 = 0xFFFFFFFFu;
        if (bas + 15u >= vv) r15 = 0xFFFFFFFFu;
      }
    } else {                               // fully-pad tile: no load at all
      r0=0xFFFFFFFFu; r1=0xFFFFFFFFu; r2=0xFFFFFFFFu; r3=0xFFFFFFFFu;
      r4=0xFFFFFFFFu; r5=0xFFFFFFFFu; r6=0xFFFFFFFFu; r7=0xFFFFFFFFu;
      r8=0xFFFFFFFFu; r9=0xFFFFFFFFu; r10=0xFFFFFFFFu; r11=0xFFFFFFFFu;
      r12=0xFFFFFFFFu; r13=0xFFFFFFFFu; r14=0xFFFFFFFFu; r15=0xFFFFFFFFu;
    }
    bool D = ((bas & 16u) == 0u);
    SORT16F(D);
    STORETILE16(lds4);
  }
  if (wact) {
    for (u32 k = 32u; k <= Lw; k <<= 1) {
      wave_tail(lds4, RU, Lw, 0u, k, k >> 1, lane);
      if (act) {
        LOADTILE16(lds4);
        bool D = ((bas & k) == 0u);
        MERGE16F(D);
        STORETILE16(lds4);
      }
    }
  }

  // ---- Phase B: cross-wave stages (W >= 2048)
  if (W >= 2048u) {
    __syncthreads();
    for (u32 k = 2048u; k <= W; k <<= 1) {
      u32 jt = k >> 1;
      if (jt >= 8192u) {                  // k = 16384: strides 8192..1024
        cross3(lds4, W, 0u, k, 8192u, tid);
        __syncthreads();
        cross1(lds4, W, 0u, k, 1024u, tid);
        __syncthreads();
      } else if (jt == 4096u) {
        cross3(lds4, W, 0u, k, 4096u, tid);
        __syncthreads();
      } else if (jt == 2048u) {
        cross2(lds4, W, 0u, k, 2048u, tid);
        __syncthreads();
      } else {
        cross1(lds4, W, 0u, k, 1024u, tid);
        __syncthreads();
      }
      if (wact) {
        wave_tail(lds4, RU, Lw, 0u, k, 512u, lane);
        if (act) {
          LOADTILE16(lds4);
          bool D = ((bas & k) == 0u);
          MERGE16F(D);
          STORETILE16(lds4);
        }
      }
      if (k < W) __syncthreads();
    }
  }

  // ---- lane-striped dense write-out.
  // Small clusters: only ceil(v/4) uint4s (tail is register-pad territory,
  // nothing downstream reads it). Big clusters: full W.
  __syncthreads();
  u32 ulim = (pc > CHUNK) ? (W >> 2) : (((u32)v + 3u) >> 2);
  for (u32 uu = tid; uu < ulim; uu += STH) {
    uint4 q = lds4[U4(uu)];
    q.x ^= inv; q.y ^= inv; q.z ^= inv; q.w ^= inv;
    gp4[uu] = q;
  }
}

// ---------------- K6: global bitonic pass for big segments (j >= CHUNK).
__global__ __launch_bounds__(256) void k_gpass(
    u32* __restrict__ vbase, const int* __restrict__ pG, const int* __restrict__ pOffG,
    int kk, int j)
{
  u32* base = vbase + (size_t)blockIdx.y * SEG_STRIDE;
  int pb[KCL]; int tot = 0;
#pragma unroll
  for (int c = 0; c < KCL; ++c) {
    pb[c] = tot;
    int pc = pG[c];
    if (pc >= kk) tot += pc >> 1;
  }
  for (int g4 = (blockIdx.x * 256 + threadIdx.x) << 2; g4 < tot; g4 += gridDim.x * 256 * 4) {
    int c = 0;
#pragma unroll
    for (int cc = 1; cc < KCL; ++cc) c += (g4 >= pb[cc]) ? 1 : 0;
    int u = g4 - pb[c];
    int i = ((u & ~(j - 1)) << 1) | (u & (j - 1));
    bool up = ((i & kk) == 0);
    u32* s2 = base + pOffG[c];
    uint4 A = *(const uint4*)(s2 + i);
    uint4 B = *(const uint4*)(s2 + i + j);
    CS(A.x, B.x, up) CS(A.y, B.y, up) CS(A.z, B.z, up) CS(A.w, B.w, up)
    *(uint4*)(s2 + i) = A;
    *(uint4*)(s2 + i + j) = B;
  }
}

// ---------------- K7: finish big-segment stage (strides <= 8192) in 64KB LDS.
__global__ __launch_bounds__(STH) void k_gfinish(
    u32* __restrict__ vbase, const int* __restrict__ pG, const int* __restrict__ pOffG, int kk)
{
  __shared__ __align__(16) u32 lds[CHUNK];
  uint4* lds4 = (uint4*)lds;
  int t = blockIdx.x, c = -1, sub = 0, acc = 0;
  for (int cc = 0; cc < KCL; ++cc) {
    int pc = pG[cc];
    if (pc < kk) continue;
    int nc = pc / CHUNK;
    if (t < acc + nc) { c = cc; sub = t - acc; break; }
    acc += nc;
  }
  if (c < 0) return;
  u32 gb = (u32)sub * (u32)CHUNK;
  u32* seg = vbase + (size_t)blockIdx.y * SEG_STRIDE + pOffG[c] + gb;
  uint4* gp4 = (uint4*)seg;
  u32 tid = threadIdx.x;
  u32 lane = tid & 63u;
  u32 wv = tid >> 6;
  u32 RU = wv << 8;
  u32 ub = tid << 2;
  u32 bas = tid << 4;
  u32 r0,r1,r2,r3,r4,r5,r6,r7,r8,r9,r10,r11,r12,r13,r14,r15;

  for (u32 uu = tid; uu < CHUNK / 4; uu += STH) lds4[U4(uu)] = gp4[uu];
  __syncthreads();
  cross3(lds4, (u32)CHUNK, gb, (u32)kk, 8192u, tid);   // strides 8192..2048
  __syncthreads();
  cross1(lds4, (u32)CHUNK, gb, (u32)kk, 1024u, tid);   // stride 1024
  __syncthreads();
  wave_tail(lds4, RU, 1024u, gb, (u32)kk, 512u, lane); // strides 512..16
  {
    LOADTILE16(lds4);
    bool up = (((gb + bas) & (u32)kk) == 0u);
    MERGE16F(up);
    STORETILE16(lds4);
  }
  __syncthreads();
  for (u32 uu = tid; uu < CHUNK / 4; uu += STH) gp4[uu] = lds4[U4(uu)];
}

// ---------------- K8: windowed |diff| reduce over valid positions only.
__global__ __launch_bounds__(256) void k_reduce(
    const u32* __restrict__ valX, const u32* __restrict__ valT,
    const int* __restrict__ pOffG, const int* __restrict__ mOffG,
    const int* __restrict__ nloG,
    const float* __restrict__ wG, float* __restrict__ lossAcc)
{
  __shared__ int spOff[KCL];
  __shared__ int smo[KCL + 1];
  __shared__ int snlo[KCL];
  __shared__ float swt[KCL];
  __shared__ float red[256];
  int tid = threadIdx.x;
  if (tid <= KCL) smo[tid] = mOffG[tid];
  if (tid < KCL) { spOff[tid] = pOffG[tid]; snlo[tid] = nloG[tid]; swt[tid] = wG[tid]; }
  __syncthreads();
  int d = blockIdx.y;
  const u32* vx = valX + (size_t)d * SEG_STRIDE;
  const u32* vt = valT + (size_t)d * SEG_STRIDE;
  int M = smo[KCL];
  float s = 0.f;
  for (int w = blockIdx.x * 256 + tid; w < M; w += gridDim.x * 256) {
    int c = 0;
#pragma unroll
    for (int cc = 1; cc < KCL; ++cc) c += (w >= smo[cc]) ? 1 : 0;
    int pos = spOff[c] + snlo[c] + (w - smo[c]);
    float a = dec_f(vx[pos]), b = dec_f(vt[pos]);
    s += fabsf(a - b) * swt[c];
  }
  red[tid] = s;
  __syncthreads();
  for (int st = 128; st > 0; st >>= 1) {
    if (tid < st) red[tid] += red[tid + st];
    __syncthreads();
  }
  if (tid == 0) atomicAdd(lossAcc, red[0]);
}

// ---------------- K9: final scalar
__global__ void k_final(const float* __restrict__ lossAcc, const float* __restrict__ loss_fil,
                        float* __restrict__ out)
{
  out[0] = *lossAcc + *loss_fil;
}

extern "C" void kernel_launch(void* const* d_in, const int* in_sizes, int n_in,
                              void* d_out, int out_size, void* d_ws, size_t ws_size,
                              hipStream_t stream)
{
  const float* x       = (const float*)d_in[0];
  const float* centers = (const float*)d_in[1];
  const float* ftarget = (const float*)d_in[2];
  const float* tgt     = (const float*)d_in[3];
  const int*   predT   = (const int*)d_in[4];
  float* out = (float*)d_out;

  char* ws = (char*)d_ws;
  float* fill_sum = (float*)(ws + 0);       // 16 f (zeroed)
  float* lossAcc  = (float*)(ws + 64);      // zeroed
  float* loss_fil = (float*)(ws + 68);      // zeroed
  int*   m_buf    = (int*)(ws + 128);
  float* w_buf    = (float*)(ws + 192);
  int*   p_buf    = (int*)(ws + 256);
  int*   pOff     = (int*)(ws + 320);       // 17 ints
  int*   mOff     = (int*)(ws + 400);       // 17 ints
  u32* histX = (u32*)(ws + 512);            // 512*16*4 = 32768
  u32* histT = (u32*)(ws + 512 + 32768);
  u32* baseX = (u32*)(ws + 512 + 65536);
  u32* baseT = (u32*)(ws + 512 + 98304);
  int* predX = (int*)(ws + 131584);         // 524288
  int* idxX  = (int*)(ws + 655872);         // 524288 (compact, Sum(m) <= 131072)
  int* idxT  = (int*)(ws + 1180160);        // 524288
  int* nlo_buf = (int*)(ws + 1704448);      // 16 ints
  u32* vbase = (u32*)(ws + VOFF);

  size_t avail_elems = (ws_size > VOFF) ? ((ws_size - VOFF) / 4) : 0;
  int Db = (int)(avail_elems / (2ull * SEG_STRIDE));
  if (Db > DIMS) Db = DIMS;
  if (Db >= 4) Db &= ~3;
  if (Db < 1) Db = 1;

  hipMemsetAsync(ws, 0, 128, stream);
  k_assign<<<NBLK, 256, 0, stream>>>(x, centers, predT, predX, fill_sum, histX, histT);
  k_scan<<<1, 512, 0, stream>>>(histX, histT, baseX, baseT, fill_sum, ftarget,
                                m_buf, w_buf, p_buf, pOff, mOff, nlo_buf, loss_fil);
  k_rank<<<NBLK, 256, 0, stream>>>(predX, predT, baseX, baseT, m_buf, mOff, idxX, idxT);

  for (int d0 = 0; d0 < DIMS; d0 += Db) {
    int Dbc = (Db < DIMS - d0) ? Db : (DIMS - d0);
    u32* valX = vbase;
    u32* valT = vbase + (size_t)Dbc * SEG_STRIDE;
    // 1028 * 256 = 263168 >= worst-case Sum(p); values + pads in one pass
    k_gather<<<1028, 256, 0, stream>>>(x, tgt, idxX, idxT, pOff, mOff, m_buf, p_buf,
                                       valX, valT, d0, Dbc);
    // worst-case chunk count: Sum max(1, p/16384) <= 26 -> 28 x-blocks (extras exit)
    k_sort<<<dim3(28, 2 * Dbc), STH, 0, stream>>>(vbase, p_buf, pOff, m_buf);
    // parallel merge stages for clusters with p > 16384 (early-exit when none)
    for (int kk = 2 * CHUNK; kk <= N_ROWS; kk <<= 1) {
      int gx = (kk == 2 * CHUNK) ? 32 : 8;
      for (int j = kk >> 1; j >= CHUNK; j >>= 1)
        k_gpass<<<dim3(gx, 2 * Dbc), 256, 0, stream>>>(vbase, p_buf, pOff, kk, j);
      // chunks with p >= kk bounded by Sum(p)/CHUNK <= 16 -> 18 x-blocks
      k_gfinish<<<dim3(18, 2 * Dbc), STH, 0, stream>>>(vbase, p_buf, pOff, kk);
    }
    k_reduce<<<dim3(32, Dbc), 256, 0, stream>>>(valX, valT, pOff, mOff, nlo_buf,
                                                w_buf, lossAcc);
  }
  k_final<<<1, 1, 0, stream>>>(lossAcc, loss_fil, out);
}